// Round 7
// baseline (432.310 us; speedup 1.0000x reference)
//
#include <hip/hip_runtime.h>
#include <math.h>

#define B_ 2
#define T_ 4096
#define E_ 1024
#define H_ 16
#define D_ 64
#define P_ 64
#define M_ 8
#define CH_ 256
#define NC_ 16
#define F_ 512
#define BH_ 32
#define BT_ 8192

// ---- workspace layout ----
static constexpr size_t SZ_BHTD = (size_t)B_ * H_ * T_ * D_;     // 8,388,608
static constexpr size_t SZ_PRF  = (size_t)B_ * H_ * T_ * M_;     // 1,048,576
static constexpr size_t SZ_KS   = (size_t)NC_ * BH_ * F_;        // 262,144
static constexpr size_t SZ_NRM  = (size_t)NC_ * BH_ * CH_;       // 131,072
static constexpr size_t SZ_KV_E = 33554432;                      // bf16 region

static constexpr size_t OFF_Q   = 0;
static constexpr size_t OFF_K   = OFF_Q + SZ_BHTD;
static constexpr size_t OFF_V   = OFF_K + SZ_BHTD;    // v bf16 (half used); woutb overlay later
static constexpr size_t OFF_FQ  = OFF_V + SZ_BHTD;
static constexpr size_t OFF_FK  = OFF_FQ + SZ_PRF;
static constexpr size_t OFF_KS  = OFF_FK + SZ_PRF;
static constexpr size_t OFF_NRM = OFF_KS + SZ_KS;
static constexpr size_t OFF_O   = OFF_NRM + SZ_NRM;
static constexpr size_t OFF_KV  = OFF_O + SZ_BHTD;
// total = OFF_KV*4 + SZ_KV_E*2 = 211,288,064 B (~201.5 MiB)

__device__ __forceinline__ float bf2f(unsigned short u) {
  union { unsigned u32; float f; } x; x.u32 = ((unsigned)u) << 16; return x.f;
}
__device__ __forceinline__ unsigned short f2bf(float f) {
  union { float f; unsigned u; } x; x.f = f;
  unsigned r = x.u + 0x7fffu + ((x.u >> 16) & 1u);
  return (unsigned short)(r >> 16);
}

typedef short v8s __attribute__((ext_vector_type(8)));
typedef float f32x4 __attribute__((ext_vector_type(4)));
typedef float f32x16 __attribute__((ext_vector_type(16)));
#define LDSA 72   // GEMM LDS stride (bf16) for the remaining 128-tile GEMMs

// ---------------------------------------------------------------------------
__global__ __launch_bounds__(256) void k_split_x(
    const float* __restrict__ x, unsigned short* __restrict__ hi,
    unsigned short* __restrict__ lo) {
  const size_t i4 = ((size_t)blockIdx.x * 256 + threadIdx.x) * 4;
  const float4 v = *(const float4*)(x + i4);
  ushort4 h, l;
  h.x = f2bf(v.x); l.x = f2bf(v.x - bf2f(h.x));
  h.y = f2bf(v.y); l.y = f2bf(v.y - bf2f(h.y));
  h.z = f2bf(v.z); l.z = f2bf(v.z - bf2f(h.z));
  h.w = f2bf(v.w); l.w = f2bf(v.w - bf2f(h.w));
  *(ushort4*)(hi + i4) = h;
  *(ushort4*)(lo + i4) = l;
}

__global__ __launch_bounds__(256) void k_cast_w(
    const float* __restrict__ w, unsigned short* __restrict__ wb) {
  const size_t i4 = ((size_t)blockIdx.x * 256 + threadIdx.x) * 4;
  const float4 v = *(const float4*)(w + i4);
  ushort4 h;
  h.x = f2bf(v.x); h.y = f2bf(v.y); h.z = f2bf(v.z); h.w = f2bf(v.w);
  *(ushort4*)(wb + i4) = h;
}

// ---------------------------------------------------------------------------
// Q/K GEMM, round-12 (resubmit of round-6; infra flake, kernel never ran):
// r10 pipeline, MFMA shape 16x16x32 -> 32x32x16 (2382 vs 2075 TF ubench;
// half the MFMA instructions and lgkm events per step; same register totals).
// Same chunk-XOR involution stays conflict-free for the 32x32 read pattern.
// Branch-free steady-state loop (peeled tail).
// C/D mapping (m74/m101): col=lane&31, row=(reg&3)+8*(reg>>2)+4*(lane>>5).
// K virtual 2048: tiles 0..31 read xhi, 32..63 read xlo; B wraps mod 1024.
// grid = (32, 8), block = 512.
// ---------------------------------------------------------------------------
__global__ __launch_bounds__(512) void k_qk_mfma8(
    const unsigned short* __restrict__ xhi, const unsigned short* __restrict__ xlo,
    const unsigned short* __restrict__ wb, const float* __restrict__ bias,
    float* __restrict__ qb, float* __restrict__ kb) {
  __shared__ __align__(16) unsigned short LA[4][8192];   // 4 slots x 256 rows x 32 K
  __shared__ __align__(16) unsigned short LB[4][8192];   // 64 KiB + 64 KiB
  const int bt0 = blockIdx.x * 256, j0 = blockIdx.y * 256;
  const int tid = threadIdx.x;
  const int lane = tid & 63, w = tid >> 6;
  const int wr = w >> 2, wc = w & 3;          // 2 M-groups x 4 N-groups
  const int lane31 = lane & 31, hi = lane >> 5;
  const int lkey = (lane31 >> 1) & 3;         // read-side swizzle key
  f32x16 acc[4][2] = {};
  v8s rA0[4][2], rB0[2][2], rA1[4][2], rB1[2][2];

  const int o0 = tid * 8;          // short offset of chunk 0 (dest, linear)
  const int row0 = tid >> 2;       // 0..127
  const int cb0 = (((tid & 3) ^ ((tid >> 3) & 3))) * 8;   // swizzled src shorts

#define QK_STAGE_A(kt)                                                        \
  {                                                                           \
    const unsigned short* ab_ = ((kt) < 32) ? xhi : xlo;                      \
    const int kc_ = ((kt) & 31) * 32;                                         \
    __builtin_amdgcn_global_load_lds(                                         \
        (const __attribute__((address_space(1))) void*)(ab_ +                 \
            (size_t)(bt0 + row0) * E_ + kc_ + cb0),                           \
        (__attribute__((address_space(3))) void*)&LA[(kt) & 3][o0], 16, 0, 0);\
    __builtin_amdgcn_global_load_lds(                                         \
        (const __attribute__((address_space(1))) void*)(ab_ +                 \
            (size_t)(bt0 + 128 + row0) * E_ + kc_ + cb0),                     \
        (__attribute__((address_space(3))) void*)&LA[(kt) & 3][o0 + 4096],    \
        16, 0, 0);                                                            \
  }
#define QK_STAGE_B(kt)                                                        \
  {                                                                           \
    const int kc_ = ((kt) & 31) * 32;                                         \
    __builtin_amdgcn_global_load_lds(                                         \
        (const __attribute__((address_space(1))) void*)(wb +                  \
            (size_t)(j0 + row0) * E_ + kc_ + cb0),                            \
        (__attribute__((address_space(3))) void*)&LB[(kt) & 3][o0], 16, 0, 0);\
    __builtin_amdgcn_global_load_lds(                                         \
        (const __attribute__((address_space(1))) void*)(wb +                  \
            (size_t)(j0 + 128 + row0) * E_ + kc_ + cb0),                      \
        (__attribute__((address_space(3))) void*)&LB[(kt) & 3][o0 + 4096],    \
        16, 0, 0);                                                            \
  }
// full fragment set for one K-step: 8 A (4 Mtiles x 2 kk) + 4 B (2 Nt x 2 kk)
#define QK_READ_FULL(RA, RB, kt)                                              \
  {                                                                           \
    _Pragma("unroll") for (int kk_ = 0; kk_ < 2; ++kk_) {                     \
      const int ch_ = ((kk_ * 2 + hi) ^ lkey) * 8;                            \
      _Pragma("unroll") for (int mt_ = 0; mt_ < 4; ++mt_) {                   \
        const int row_ = wr * 128 + mt_ * 32 + lane31;                        \
        RA[mt_][kk_] = *(const v8s*)&LA[(kt) & 3][row_ * 32 + ch_];           \
      }                                                                       \
      _Pragma("unroll") for (int nt_ = 0; nt_ < 2; ++nt_) {                   \
        const int row_ = wc * 64 + nt_ * 32 + lane31;                         \
        RB[nt_][kk_] = *(const v8s*)&LB[(kt) & 3][row_ * 32 + ch_];           \
      }                                                                       \
    }                                                                         \
  }
#define QK_MFMA_ALL(RA, RB)                                                   \
  __builtin_amdgcn_s_setprio(1);                                              \
  _Pragma("unroll") for (int kk_ = 0; kk_ < 2; ++kk_)                         \
    _Pragma("unroll") for (int mt_ = 0; mt_ < 4; ++mt_)                       \
      _Pragma("unroll") for (int nt_ = 0; nt_ < 2; ++nt_)                     \
        acc[mt_][nt_] = __builtin_amdgcn_mfma_f32_32x32x16_bf16(              \
            RA[mt_][kk_], RB[nt_][kk_], acc[mt_][nt_], 0, 0, 0);              \
  __builtin_amdgcn_s_setprio(0);

  // prologue: stage tiles 0..3 (16 loads/thread); drain tiles 0,1,2.
  QK_STAGE_A(0); QK_STAGE_B(0);
  QK_STAGE_A(1); QK_STAGE_B(1);
  QK_STAGE_A(2); QK_STAGE_B(2);
  QK_STAGE_A(3); QK_STAGE_B(3);
  asm volatile("s_waitcnt vmcnt(4)" ::: "memory");
  asm volatile("s_barrier" ::: "memory");
  QK_READ_FULL(rA0, rB0, 0);
  asm volatile("s_waitcnt lgkmcnt(0)" ::: "memory");  // slot0 reads done before
                                                      // slot0 re-staged (tile 4)

  // steady state: branch-free. Invariant at body s: regs hold tile s; tiles
  // through s+3 staged & drained appropriately; vmcnt(4) leaves tile s+5.
#pragma unroll 1
  for (int s = 0; s < 60; s += 2) {
    QK_READ_FULL(rA1, rB1, s + 1);
    QK_STAGE_A(s + 4); QK_STAGE_B(s + 4);
    QK_MFMA_ALL(rA0, rB0);
    QK_READ_FULL(rA0, rB0, s + 2);
    QK_STAGE_A(s + 5); QK_STAGE_B(s + 5);
    QK_MFMA_ALL(rA1, rB1);
    asm volatile("s_waitcnt vmcnt(4)" ::: "memory");
    asm volatile("s_barrier" ::: "memory");
  }
  // s = 60: no stages remain; drain last tile (63)
  QK_READ_FULL(rA1, rB1, 61);
  QK_MFMA_ALL(rA0, rB0);
  QK_READ_FULL(rA0, rB0, 62);
  QK_MFMA_ALL(rA1, rB1);
  asm volatile("s_waitcnt vmcnt(0)" ::: "memory");
  asm volatile("s_barrier" ::: "memory");
  // s = 62
  QK_READ_FULL(rA1, rB1, 63);
  QK_MFMA_ALL(rA0, rB0);
  QK_MFMA_ALL(rA1, rB1);

#undef QK_MFMA_ALL
#undef QK_READ_FULL
#undef QK_STAGE_B
#undef QK_STAGE_A

  // epilogue: 32x32 C/D mapping col=lane&31, row=(reg&3)+8*(reg>>2)+4*hi
#pragma unroll
  for (int nt = 0; nt < 2; ++nt) {
    const int n = j0 + wc * 64 + nt * 32 + lane31;
    const int sec = n >> 10, nn = n & 1023, h = nn >> 6, dd = nn & 63;
    float* dst = (sec == 0) ? qb : kb;
    const float bv = bias[n];
#pragma unroll
    for (int mt = 0; mt < 4; ++mt) {
#pragma unroll
      for (int rg = 0; rg < 16; ++rg) {
        const int m = bt0 + wr * 128 + mt * 32 + (rg & 3) + 8 * (rg >> 2) + 4 * hi;
        const int b = m >> 12, t = m & (T_ - 1);
        dst[((size_t)(b * H_ + h) * T_ + t) * D_ + dd] = acc[mt][nt][rg] + bv;
      }
    }
  }
}

// ---------------------------------------------------------------------------
// V GEMM via MFMA, hi-only bf16 A, bf16 out. Branch-free. grid = (64, 8).
// ---------------------------------------------------------------------------
__global__ __launch_bounds__(256) void k_v_mfma(
    const unsigned short* __restrict__ xhi, const unsigned short* __restrict__ wb,
    const float* __restrict__ bias, unsigned short* __restrict__ vbf) {
  __shared__ __align__(16) unsigned short Ah[128 * LDSA];
  __shared__ __align__(16) unsigned short Bs[128 * LDSA];
  const int bt0 = blockIdx.x * 128, j0 = blockIdx.y * 128;
  const int tid = threadIdx.x;
  const int lane = tid & 63, wave = tid >> 6;
  const int wm = (wave & 1) * 64, wn = (wave >> 1) * 64;
  const int col = lane & 15, quad = lane >> 4;
  f32x4 acc[4][4] = {};
  const int sr = tid >> 3, sg = tid & 7;

  for (int k0 = 0; k0 < E_; k0 += 64) {
    __syncthreads();
#pragma unroll
    for (int it = 0; it < 4; ++it) {
      const int r = it * 32 + sr;
      *(v8s*)&Ah[r * LDSA + sg * 8] =
          *(const v8s*)(xhi + (size_t)(bt0 + r) * E_ + k0 + sg * 8);
      *(v8s*)&Bs[r * LDSA + sg * 8] =
          *(const v8s*)(wb + (size_t)(2048 + j0 + r) * E_ + k0 + sg * 8);
    }
    __syncthreads();
#pragma unroll
    for (int kk = 0; kk < 2; ++kk) {
      v8s ah[4], bfr[4];
#pragma unroll
      for (int i = 0; i < 4; ++i) {
        ah[i] = *(const v8s*)&Ah[(wm + i * 16 + col) * LDSA + kk * 32 + quad * 8];
        bfr[i] = *(const v8s*)&Bs[(wn + i * 16 + col) * LDSA + kk * 32 + quad * 8];
      }
#pragma unroll
      for (int i = 0; i < 4; ++i)
#pragma unroll
        for (int j = 0; j < 4; ++j)
          acc[i][j] = __builtin_amdgcn_mfma_f32_16x16x32_bf16(ah[i], bfr[j], acc[i][j], 0, 0, 0);
    }
  }
#pragma unroll
  for (int j = 0; j < 4; ++j) {
    const int n = j0 + wn + j * 16 + col;   // 0..1023 within v section
    const int h = n >> 6, dd = n & 63;
    const float bv = bias[2048 + n];
#pragma unroll
    for (int i = 0; i < 4; ++i) {
      const int mbase = bt0 + wm + i * 16 + quad * 4;
#pragma unroll
      for (int r = 0; r < 4; ++r) {
        const int m = mbase + r;
        const int b = m >> 12, t = m & (T_ - 1);
        vbf[((size_t)(b * H_ + h) * T_ + t) * D_ + dd] = f2bf(acc[i][j][r] + bv);
      }
    }
  }
}

// ---------------------------------------------------------------------------
// Features via MFMA (unchanged from round 6)
// ---------------------------------------------------------------------------
__global__ __launch_bounds__(256) void k_feat_mfma(
    const float* __restrict__ xin, const float* __restrict__ poly_w,
    const float* __restrict__ omega, const float* __restrict__ qnod,
    const float* __restrict__ qwt, unsigned short* __restrict__ pqb,
    unsigned short* __restrict__ fqb) {
  __shared__ __align__(16) unsigned short XH[128 * 72];
  __shared__ __align__(16) unsigned short XL[128 * 72];
  __shared__ __align__(16) unsigned short Bs[80 * 72];
  const int bh = blockIdx.x >> 5;
  const int t0 = (blockIdx.x & 31) * 128;
  const int h = bh & (H_ - 1);
  const int tid = threadIdx.x, lane = tid & 63, w = tid >> 6;
  const int col = lane & 15, quad = lane >> 4;
  const size_t rowB = (size_t)bh * T_ + t0;

  const float s0 = qnod[0];
  const float sq2 = sqrtf(fmaxf(2.f * s0, 0.f));
  const float scale = sqrtf(fmaxf(qwt[0], 0.f)) * 0.3535533905932738f;

  for (int rr = 0; rr < 32; ++rr) {
    const int t = w * 32 + rr;
    const float xv = xin[(rowB + t) * D_ + lane];
    float ss = xv * xv;
#pragma unroll
    for (int off = 32; off > 0; off >>= 1) ss += __shfl_xor(ss, off);
    const float rn = 1.0f / fmaxf(sqrtf(ss), 1e-12f);
    const float xn = xv * rn;
    const unsigned short hi = f2bf(xn);
    XH[t * 72 + lane] = hi;
    XL[t * 72 + lane] = f2bf(xn - bf2f(hi));
  }
  {
    const int base = tid * 16;
#pragma unroll
    for (int j4 = 0; j4 < 4; ++j4) {
      const int idx = base + j4 * 4;
      const int d = idx >> 6, p = idx & 63;
      const float4 v = *(const float4*)(poly_w + (size_t)h * 4096 + idx);
      Bs[(p + 0) * 72 + d] = f2bf(v.x);
      Bs[(p + 1) * 72 + d] = f2bf(v.y);
      Bs[(p + 2) * 72 + d] = f2bf(v.z);
      Bs[(p + 3) * 72 + d] = f2bf(v.w);
    }
    if (tid < 128) {
      const int idx = tid * 4;
      const int d = idx >> 3, m0 = idx & 7;
      const float4 v = *(const float4*)(omega + (size_t)h * 512 + idx);
      Bs[(64 + m0 + 0) * 72 + d] = f2bf(v.x);
      Bs[(64 + m0 + 1) * 72 + d] = f2bf(v.y);
      Bs[(64 + m0 + 2) * 72 + d] = f2bf(v.z);
      Bs[(64 + m0 + 3) * 72 + d] = f2bf(v.w);
    }
  }
  __syncthreads();
  f32x4 acc[2][5] = {};
#pragma unroll
  for (int kk = 0; kk < 2; ++kk) {
    v8s ah[2], al[2];
#pragma unroll
    for (int i = 0; i < 2; ++i) {
      const int mo = ((2 * w + i) * 16 + col) * 72 + kk * 32 + quad * 8;
      ah[i] = *(const v8s*)&XH[mo];
      al[i] = *(const v8s*)&XL[mo];
    }
#pragma unroll
    for (int nt = 0; nt < 5; ++nt) {
      const v8s bb = *(const v8s*)&Bs[(nt * 16 + col) * 72 + kk * 32 + quad * 8];
#pragma unroll
      for (int i = 0; i < 2; ++i) {
        acc[i][nt] = __builtin_amdgcn_mfma_f32_16x16x32_bf16(ah[i], bb, acc[i][nt], 0, 0, 0);
        acc[i][nt] = __builtin_amdgcn_mfma_f32_16x16x32_bf16(al[i], bb, acc[i][nt], 0, 0, 0);
      }
    }
  }
#pragma unroll
  for (int i = 0; i < 2; ++i) {
#pragma unroll
    for (int r = 0; r < 4; ++r) {
      const int t = (2 * w + i) * 16 + quad * 4 + r;
#pragma unroll
      for (int nt = 0; nt < 4; ++nt) {
        const float c = acc[i][nt][r];
        pqb[(rowB + t) * P_ + nt * 16 + col] = f2bf(c * c * 0.125f);
      }
      if (col < 8) {
        const float c = acc[i][4][r];
        const float z = fminf(fmaxf(c * sq2 - s0, -20.f), 20.f);
        fqb[(rowB + t) * M_ + col] = f2bf(expf(z) * scale);
      }
    }
  }
}

// ---------------------------------------------------------------------------
// Phase A via MFMA (unchanged from round 6)
// ---------------------------------------------------------------------------
__global__ __launch_bounds__(512) void k_phaseA(
    const unsigned short* __restrict__ pkb, const unsigned short* __restrict__ fkb,
    const unsigned short* __restrict__ vbf, unsigned short* __restrict__ kvch,
    float* __restrict__ ksum) {
  __shared__ __align__(16) unsigned short VT[64 * 72];
  __shared__ __align__(16) unsigned short pkT[64 * 72];
  __shared__ __align__(16) unsigned short fkT[8 * 72];
  const int bh = blockIdx.x & (BH_ - 1);
  const int c = blockIdx.x >> 5;
  const size_t rowC = (size_t)bh * T_ + (size_t)c * CH_;
  const int tid = threadIdx.x, lane = tid & 63, w = tid >> 6;
  const int col = lane & 15, quad = lane >> 4;
  const int nb = w * 64;
  f32x4 acc[4][4] = {};
  float ks[4] = {0.f, 0.f, 0.f, 0.f};

  for (int st = 0; st < 4; ++st) {
    const size_t t0 = rowC + st * 64;
    __syncthreads();
#pragma unroll
    for (int ps = 0; ps < 2; ++ps) {
      const int idx = ps * 512 + tid;
      const int t = idx >> 4, dg = (idx & 15) * 4;
      const ushort4 v = *(const ushort4*)(vbf + (t0 + t) * D_ + dg);
      VT[(dg + 0) * 72 + t] = v.x;
      VT[(dg + 1) * 72 + t] = v.y;
      VT[(dg + 2) * 72 + t] = v.z;
      VT[(dg + 3) * 72 + t] = v.w;
    }
    {
      const int t = tid >> 3, pg = (tid & 7) * 8;
      const v8s pv = *(const v8s*)(pkb + (t0 + t) * P_ + pg);
#pragma unroll
      for (int j = 0; j < 8; ++j) pkT[(pg + j) * 72 + t] = (unsigned short)pv[j];
    }
    if (tid < 64) {
      const v8s fv = *(const v8s*)(fkb + (t0 + tid) * M_);
#pragma unroll
      for (int j = 0; j < 8; ++j) fkT[j * 72 + tid] = (unsigned short)fv[j];
    }
    __syncthreads();
#pragma unroll
    for (int kk = 0; kk < 2; ++kk) {
      v8s a[4];
#pragma unroll
      for (int mt = 0; mt < 4; ++mt)
        a[mt] = *(const v8s*)&VT[(mt * 16 + col) * 72 + kk * 32 + quad * 8];
#pragma unroll
      for (int nt = 0; nt < 4; ++nt) {
        const int pm = nb + nt * 16 + col;
        const int p = pm >> 3, m8 = pm & 7;
        const v8s pkv = *(const v8s*)&pkT[p * 72 + kk * 32 + quad * 8];
        const v8s fkv = *(const v8s*)&fkT[m8 * 72 + kk * 32 + quad * 8];
        v8s bfrag;
        float kss = 0.f;
#pragma unroll
        for (int j = 0; j < 8; ++j) {
          const float v = bf2f((unsigned short)pkv[j]) * bf2f((unsigned short)fkv[j]);
          kss += v;
          bfrag[j] = (short)f2bf(v);
        }
        ks[nt] += kss;
#pragma unroll
        for (int mt = 0; mt < 4; ++mt)
          acc[mt][nt] = __builtin_amdgcn_mfma_f32_16x16x32_bf16(a[mt], bfrag, acc[mt][nt], 0, 0, 0);
      }
    }
  }
  const size_t base = (size_t)(c * BH_ + bh) * D_ * F_;
#pragma unroll
  for (int nt = 0; nt < 4; ++nt) {
    const int pm = nb + nt * 16 + col;
#pragma unroll
    for (int mt = 0; mt < 4; ++mt) {
#pragma unroll
      for (int r = 0; r < 4; ++r) {
        const int d = mt * 16 + quad * 4 + r;
        kvch[base + (size_t)d * F_ + pm] = f2bf(acc[mt][nt][r]);
      }
    }
    float kv_ = ks[nt];
    kv_ += __shfl_xor(kv_, 16);
    kv_ += __shfl_xor(kv_, 32);
    if (quad == 0) ksum[(size_t)(c * BH_ + bh) * F_ + pm] = kv_;
  }
}

// ---------------------------------------------------------------------------
__global__ __launch_bounds__(256) void k_scan_kv(unsigned short* __restrict__ kvch) {
  const size_t s = (size_t)blockIdx.x * 256 + threadIdx.x;
  const size_t stride = (size_t)BH_ * D_ * F_;
  unsigned short v[NC_];
#pragma unroll
  for (int c = 0; c < NC_; ++c) v[c] = kvch[(size_t)c * stride + s];
  float run = 0.f;
#pragma unroll
  for (int c = 0; c < NC_; ++c) {
    const float t = bf2f(v[c]);
    kvch[(size_t)c * stride + s] = f2bf(run);
    run += t;
  }
}

__global__ __launch_bounds__(256) void k_scan_ks(float* __restrict__ ksum) {
  const int s = blockIdx.x * 256 + threadIdx.x;
  const int stride = BH_ * F_;
  float v[NC_];
#pragma unroll
  for (int c = 0; c < NC_; ++c) v[c] = ksum[c * stride + s];
  float run = 0.f;
#pragma unroll
  for (int c = 0; c < NC_; ++c) {
    const float t = v[c];
    ksum[c * stride + s] = run;
    run += t;
  }
}

// ---------------------------------------------------------------------------
// Fused scores+intra (round-11 version: pk/fk LDS staging + 3rd-MFMA fusion)
// ---------------------------------------------------------------------------
__global__ __launch_bounds__(256) void k_sintra(
    const unsigned short* __restrict__ pqb, const unsigned short* __restrict__ fqb,
    const unsigned short* __restrict__ pkb, const unsigned short* __restrict__ fkb,
    const unsigned short* __restrict__ vbf, float* __restrict__ obuf,
    float* __restrict__ nrmbuf) {
  __shared__ __align__(16) unsigned short S_lds[128 * 136];
  __shared__ __align__(16) unsigned short VT[64 * 136];
  __shared__ __align__(16) unsigned short pkT[128 * 72];
  __shared__ __align__(16) unsigned short fkT[128 * 8];
  const int bh = blockIdx.x & (BH_ - 1);
  const int tq = blockIdx.x >> 5;
  const int c = tq >> 1, h2 = tq & 1;
  const size_t rowT = (size_t)bh * T_ + (size_t)tq * 128;
  const size_t rowC = (size_t)bh * T_ + (size_t)c * CH_;
  const int tid = threadIdx.x, lane = tid & 63, w = tid >> 6;
  const int col = lane & 15, quad = lane >> 4;

  const v8s vzero = {};
  v8s bq[2][2], bqf[2];
#pragma unroll
  for (int i = 0; i < 2; ++i) {
    const size_t qrow = rowT + (2 * w + i) * 16 + col;
    bq[i][0] = *(const v8s*)(pqb + qrow * P_ + quad * 8);
    bq[i][1] = *(const v8s*)(pqb + qrow * P_ + 32 + quad * 8);
    const v8s fv = *(const v8s*)(fqb + qrow * M_);
    bqf[i] = (quad == 0) ? fv : vzero;
  }
  f32x4 acc[2][4] = {};
  float rs[2] = {0.f, 0.f};

  const int vd = tid & 63, vg = tid >> 6;

  for (int sl = 0; sl <= h2; ++sl) {
    const size_t rowS = rowC + (size_t)sl * 128;
    __syncthreads();
    // stage pk tile 128x64 (stride-72) -- coalesced, once per block
#pragma unroll
    for (int c4 = 0; c4 < 4; ++c4) {
      const int g = c4 * 256 + tid;
      const int row = g >> 3, ch = g & 7;
      *(v8s*)&pkT[row * 72 + ch * 8] =
          *(const v8s*)(pkb + (rowS + row) * P_ + ch * 8);
    }
    // stage fk tile 128x8 (bf16)
    if (tid < 128)
      *(v8s*)&fkT[tid * 8] = *(const v8s*)(fkb + (rowS + tid) * M_);
    // stage V^T
#pragma unroll
    for (int j8 = 0; j8 < 4; ++j8) {
      const int s0 = vg * 32 + j8 * 8;
      v8s pv;
#pragma unroll
      for (int k = 0; k < 8; ++k)
        pv[k] = (short)vbf[(rowS + s0 + k) * D_ + vd];
      *(v8s*)&VT[vd * 136 + s0] = pv;
    }
    __syncthreads();
    for (int si = 0; si < 8; ++si) {
      const int srow = si * 16 + col;
      const v8s a0 = *(const v8s*)&pkT[srow * 72 + quad * 8];
      const v8s a1 = *(const v8s*)&pkT[srow * 72 + 32 + quad * 8];
      const v8s af = (quad == 0) ? *(const v8s*)&fkT[srow * 8] : vzero;
#pragma unroll
      for (int i = 0; i < 2; ++i) {
        const int tt = 2 * w + i;
        const int t_rel = h2 * 128 + tt * 16 + col;
        f32x4 sp = {};
        sp = __builtin_amdgcn_mfma_f32_16x16x32_bf16(a0, bq[i][0], sp, 0, 0, 0);
        sp = __builtin_amdgcn_mfma_f32_16x16x32_bf16(a1, bq[i][1], sp, 0, 0, 0);
        f32x4 spf = {};
        spf = __builtin_amdgcn_mfma_f32_16x16x32_bf16(af, bqf[i], spf, 0, 0, 0);
        ushort4 pk4;
        float partial = 0.f;
#pragma unroll
        for (int r = 0; r < 4; ++r) {
          const int s_in = si * 16 + quad * 4 + r;
          float val = sp[r] * spf[r];
          const int s_rel = sl * 128 + s_in;
          val = (s_rel <= t_rel) ? val : 0.f;
          partial += val;
          ((unsigned short*)&pk4)[r] = f2bf(val);
        }
        rs[i] += partial;
        *(ushort4*)&S_lds[(tt * 16 + col) * 136 + si * 16 + quad * 4] = pk4;
      }
    }
    __syncthreads();
#pragma unroll
    for (int i = 0; i < 2; ++i) {
      const int tt = 2 * w + i;
#pragma unroll
      for (int kk = 0; kk < 4; ++kk) {
        const v8s sa = *(const v8s*)&S_lds[(tt * 16 + col) * 136 + kk * 32 + quad * 8];
#pragma unroll
        for (int dt = 0; dt < 4; ++dt) {
          const v8s vb8 = *(const v8s*)&VT[(dt * 16 + col) * 136 + kk * 32 + quad * 8];
          acc[i][dt] = __builtin_amdgcn_mfma_f32_16x16x32_bf16(sa, vb8, acc[i][dt], 0, 0, 0);
        }
      }
    }
  }
#pragma unroll
  for (int i = 0; i < 2; ++i) {
#pragma unroll
    for (int dt = 0; dt < 4; ++dt) {
#pragma unroll
      for (int r = 0; r < 4; ++r) {
        const int t = (2 * w + i) * 16 + quad * 4 + r;
        obuf[(rowT + t) * D_ + dt * 16 + col] = acc[i][dt][r];
      }
    }
    rs[i] += __shfl_xor(rs[i], 16);
    rs[i] += __shfl_xor(rs[i], 32);
  }
  if (lane < 16) {
    const size_t nbase = (size_t)(c * BH_ + bh) * CH_ + h2 * 128;
    nrmbuf[nbase + (2 * w + 0) * 16 + lane] = rs[0];
    nrmbuf[nbase + (2 * w + 1) * 16 + lane] = rs[1];
  }
}

// ---------------------------------------------------------------------------
// Hist via MFMA (unchanged)
// ---------------------------------------------------------------------------
__global__ __launch_bounds__(256) void k_hist(
    const unsigned short* __restrict__ pqb, const unsigned short* __restrict__ fqb,
    const unsigned short* __restrict__ kvch, const float* __restrict__ ksum,
    const float* __restrict__ nrmbuf, const float* __restrict__ obuf,
    unsigned short* __restrict__ obf) {
  __shared__ __align__(16) unsigned short QF_lds[128 * 72];
  __shared__ __align__(16) unsigned short KV_lds[64 * 72];
  __shared__ float kp_lds[F_];
  __shared__ float nhs[128];
  const int half = blockIdx.x & 1;
  const int bh = (blockIdx.x >> 1) & (BH_ - 1);
  const int c = blockIdx.x >> 6;
  const int b = bh >> 4, h = bh & (H_ - 1);
  const int tid = threadIdx.x, lane = tid & 63, w = tid >> 6;
  const int col = lane & 15, quad = lane >> 4;
  const size_t rowQ = (size_t)bh * T_ + (size_t)c * CH_ + half * 128;
  const size_t kvbase = (size_t)(c * BH_ + bh) * D_ * F_;

  const int tr = tid >> 1, side = tid & 1;
  float fqr[8];
  {
    const v8s fv = *(const v8s*)(fqb + (rowQ + tr) * M_);
#pragma unroll
    for (int j = 0; j < 8; ++j) fqr[j] = bf2f((unsigned short)fv[j]);
    if (tid < 128)
      *(float4*)(&kp_lds[tid * 4]) =
          *(const float4*)(ksum + (size_t)(c * BH_ + bh) * F_ + tid * 4);
  }
  f32x4 acc[2][4] = {};
  float nh_part = 0.f;
  const int gr = tid & 7, d0 = tid >> 3;

  for (int pmt = 0; pmt < 8; ++pmt) {
    __syncthreads();
#pragma unroll
    for (int pp = 0; pp < 2; ++pp) {
      const int d = d0 + pp * 32;
      *(v8s*)&KV_lds[d * 72 + gr * 8] =
          *(const v8s*)(kvch + kvbase + (size_t)d * F_ + pmt * 64 + gr * 8);
    }
    {
      const v8s pq8 = *(const v8s*)(pqb + (rowQ + tr) * P_ + pmt * 8);
#pragma unroll
      for (int pp = 0; pp < 4; ++pp) {
        const int pl = side * 4 + pp;
        const float pqf = bf2f((unsigned short)pq8[pl]);
        const int kb_ = (pmt * 8 + pl) * 8;
        v8s o;
#pragma unroll
        for (int j = 0; j < 8; ++j) {
          const float v = pqf * fqr[j];
          nh_part += v * kp_lds[kb_ + j];
          o[j] = (short)f2bf(v);
        }
        *(v8s*)&QF_lds[tr * 72 + pl * 8] = o;
      }
    }
    __syncthreads();
#pragma unroll
    for (int kk = 0; kk < 2; ++kk) {
      v8s a[2], bb[4];
#pragma unroll
      for (int i = 0; i < 2; ++i)
        a[i] = *(const v8s*)&QF_lds[((2 * w + i) * 16 + col) * 72 + kk * 32 + quad * 8];
#pragma unroll
      for (int j = 0; j < 4; ++j)
        bb[j] = *(const v8s*)&KV_lds[(j * 16 + col) * 72 + kk * 32 + quad * 8];
#pragma unroll
      for (int i = 0; i < 2; ++i)
#pragma unroll
        for (int j = 0; j < 4; ++j)
          acc[i][j] = __builtin_amdgcn_mfma_f32_16x16x32_bf16(a[i], bb[j], acc[i][j], 0, 0, 0);
    }
  }
  {
    const float nh = nh_part + __shfl_xor(nh_part, 1);
    if (!(tid & 1)) nhs[tr] = nh;
  }
  __syncthreads();
  const size_t nbase = (size_t)(c * BH_ + bh) * CH_ + half * 128;
#pragma unroll
  for (int i = 0; i < 2; ++i) {
#pragma unroll
    for (int r = 0; r < 4; ++r) {
      const int t = (2 * w + i) * 16 + quad * 4 + r;
      const float nrm = nhs[t] + nrmbuf[nbase + t] + 1e-6f;
      const float rcp = 1.0f / nrm;
#pragma unroll
      for (int j = 0; j < 4; ++j) {
        const int d = j * 16 + col;
        const float val = (obuf[(rowQ + t) * D_ + d] + acc[i][j][r]) * rcp;
        obf[(size_t)(b * T_ + c * CH_ + half * 128 + t) * E_ + h * 64 + d] = f2bf(val);
      }
    }
  }
}

// ---------------------------------------------------------------------------
// Out GEMM via MFMA (unchanged)
// ---------------------------------------------------------------------------
__global__ __launch_bounds__(256) void k_out_mfma(
    const unsigned short* __restrict__ ob, const unsigned short* __restrict__ wb,
    const float* __restrict__ bias, float* __restrict__ out) {
  __shared__ __align__(16) unsigned short As[128 * LDSA];
  __shared__ __align__(16) unsigned short Bs[128 * LDSA];
  const int bt0 = blockIdx.x * 128, j0 = blockIdx.y * 128;
  const int tid = threadIdx.x;
  const int lane = tid & 63, wave = tid >> 6;
  const int wm = (wave & 1) * 64, wn = (wave >> 1) * 64;
  const int col = lane & 15, quad = lane >> 4;
  f32x4 acc[4][4] = {};
  const int sr = tid >> 3, sg = tid & 7;

  for (int k0 = 0; k0 < E_; k0 += 64) {
    __syncthreads();
#pragma unroll
    for (int it = 0; it < 4; ++it) {
      const int r = it * 32 + sr;
      *(v8s*)&As[r * LDSA + sg * 8] =
          *(const v8s*)(ob + (size_t)(bt0 + r) * E_ + k0 + sg * 8);
      *(v8s*)&Bs[r * LDSA + sg * 8] =
          *(const v8s*)(wb + (size_t)(j0 + r) * E_ + k0 + sg * 8);
    }
    __syncthreads();
#pragma unroll
    for (int kk = 0; kk < 2; ++kk) {
      v8s af[4], bfr[4];
#pragma unroll
      for (int i = 0; i < 4; ++i) {
        af[i] = *(const v8s*)&As[(wm + i * 16 + col) * LDSA + kk * 32 + quad * 8];
        bfr[i] = *(const v8s*)&Bs[(wn + i * 16 + col) * LDSA + kk * 32 + quad * 8];
      }
#pragma unroll
      for (int i = 0; i < 4; ++i)
#pragma unroll
        for (int j = 0; j < 4; ++j)
          acc[i][j] = __builtin_amdgcn_mfma_f32_16x16x32_bf16(af[i], bfr[j], acc[i][j], 0, 0, 0);
    }
  }
#pragma unroll
  for (int j = 0; j < 4; ++j) {
    const int n = j0 + wn + j * 16 + col;
    const float bv = bias[n];
#pragma unroll
    for (int i = 0; i < 4; ++i) {
      const int mbase = bt0 + wm + i * 16 + quad * 4;
#pragma unroll
      for (int r = 0; r < 4; ++r)
        out[(size_t)(mbase + r) * E_ + n] = acc[i][j][r] + bv;
    }
  }
}

// ---------------------------------------------------------------------------
extern "C" void kernel_launch(void* const* d_in, const int* in_sizes, int n_in,
                              void* d_out, int out_size, void* d_ws, size_t ws_size,
                              hipStream_t stream) {
  (void)in_sizes; (void)n_in; (void)out_size; (void)ws_size;
  const float* x      = (const float*)d_in[0];
  const float* qkv_w  = (const float*)d_in[1];
  const float* qkv_b  = (const float*)d_in[2];
  const float* out_w  = (const float*)d_in[3];
  const float* out_b  = (const float*)d_in[4];
  const float* omega  = (const float*)d_in[5];
  const float* poly_w = (const float*)d_in[6];
  const float* qnod   = (const float*)d_in[7];
  const float* qwt    = (const float*)d_in[8];
  float* ws = (float*)d_ws;
  float* qb   = ws + OFF_Q;
  float* kb   = ws + OFF_K;
  unsigned short* vbf = (unsigned short*)(ws + OFF_V);
  unsigned short* fqb = (unsigned short*)(ws + OFF_FQ);
  unsigned short* fkb = (unsigned short*)(ws + OFF_FK);
  float* ksb  = ws + OFF_KS;
  float* nrmb = ws + OFF_NRM;
  float* ob   = ws + OFF_O;
  unsigned short* kvb = (unsigned short*)(ws + OFF_KV);
  unsigned short* pqb = kvb + 16777216;
  unsigned short* pkb = pqb + SZ_BHTD;
  unsigned short* xhi  = kvb;
  unsigned short* xlo  = kvb + SZ_BHTD;
  unsigned short* wqkv = kvb + 2 * SZ_BHTD;
  unsigned short* obf   = (unsigned short*)kb;
  unsigned short* woutb = (unsigned short*)(ws + OFF_V);  // over dead v (post-sintra)
  float* outp = (float*)d_out;

  hipLaunchKernelGGL(k_split_x, dim3(8192), dim3(256), 0, stream, x, xhi, xlo);
  hipLaunchKernelGGL(k_cast_w, dim3(3072), dim3(256), 0, stream, qkv_w, wqkv);
  hipLaunchKernelGGL(k_qk_mfma8, dim3(BT_ / 256, 8), dim3(512), 0, stream,
                     xhi, xlo, wqkv, qkv_b, qb, kb);
  hipLaunchKernelGGL(k_v_mfma, dim3(BT_ / 128, 8), dim3(256), 0, stream,
                     xhi, wqkv, qkv_b, vbf);
  hipLaunchKernelGGL(k_feat_mfma, dim3(1024), dim3(256), 0, stream,
                     qb, poly_w, omega, qnod, qwt, pqb, fqb);
  hipLaunchKernelGGL(k_feat_mfma, dim3(1024), dim3(256), 0, stream,
                     kb, poly_w, omega, qnod, qwt, pkb, fkb);
  hipLaunchKernelGGL(k_phaseA, dim3(NC_ * BH_), dim3(512), 0, stream,
                     pkb, fkb, vbf, kvb, ksb);
  hipLaunchKernelGGL(k_scan_kv, dim3(4096), dim3(256), 0, stream, kvb);
  hipLaunchKernelGGL(k_scan_ks, dim3(64), dim3(256), 0, stream, ksb);
  hipLaunchKernelGGL(k_sintra, dim3(BH_ * 32), dim3(256), 0, stream,
                     pqb, fqb, pkb, fkb, vbf, ob, nrmb);
  hipLaunchKernelGGL(k_cast_w, dim3(1024), dim3(256), 0, stream, out_w, woutb);
  hipLaunchKernelGGL(k_hist, dim3(NC_ * BH_ * 2), dim3(256), 0, stream,
                     pqb, fqb, kvb, ksb, nrmb, ob, obf);
  hipLaunchKernelGGL(k_out_mfma, dim3(BT_ / 128, E_ / 128), dim3(256), 0, stream,
                     obf, woutb, out_b, outp);
}

// Round 8
// 425.223 us; speedup vs baseline: 1.0167x; 1.0167x over previous
//
#include <hip/hip_runtime.h>
#include <math.h>

#define B_ 2
#define T_ 4096
#define E_ 1024
#define H_ 16
#define D_ 64
#define P_ 64
#define M_ 8
#define CH_ 256
#define NC_ 16
#define F_ 512
#define BH_ 32
#define BT_ 8192

// ---- workspace layout ----
static constexpr size_t SZ_BHTD = (size_t)B_ * H_ * T_ * D_;     // 8,388,608
static constexpr size_t SZ_PRF  = (size_t)B_ * H_ * T_ * M_;     // 1,048,576
static constexpr size_t SZ_KS   = (size_t)NC_ * BH_ * F_;        // 262,144
static constexpr size_t SZ_NRM  = (size_t)NC_ * BH_ * CH_;       // 131,072
static constexpr size_t SZ_KV_E = 33554432;                      // bf16 region

static constexpr size_t OFF_Q   = 0;
static constexpr size_t OFF_K   = OFF_Q + SZ_BHTD;
static constexpr size_t OFF_V   = OFF_K + SZ_BHTD;    // v bf16 (half used); woutb overlay later
static constexpr size_t OFF_FQ  = OFF_V + SZ_BHTD;
static constexpr size_t OFF_FK  = OFF_FQ + SZ_PRF;
static constexpr size_t OFF_KS  = OFF_FK + SZ_PRF;
static constexpr size_t OFF_NRM = OFF_KS + SZ_KS;
static constexpr size_t OFF_O   = OFF_NRM + SZ_NRM;
static constexpr size_t OFF_KV  = OFF_O + SZ_BHTD;
// total = OFF_KV*4 + SZ_KV_E*2 = 211,288,064 B (~201.5 MiB)

__device__ __forceinline__ float bf2f(unsigned short u) {
  union { unsigned u32; float f; } x; x.u32 = ((unsigned)u) << 16; return x.f;
}
__device__ __forceinline__ unsigned short f2bf(float f) {
  union { float f; unsigned u; } x; x.f = f;
  unsigned r = x.u + 0x7fffu + ((x.u >> 16) & 1u);
  return (unsigned short)(r >> 16);
}

typedef short v8s __attribute__((ext_vector_type(8)));
typedef float f32x4 __attribute__((ext_vector_type(4)));
#define LDSA 72   // GEMM LDS stride (bf16) for the remaining 128-tile GEMMs

// ---------------------------------------------------------------------------
__global__ __launch_bounds__(256) void k_split_x(
    const float* __restrict__ x, unsigned short* __restrict__ hi,
    unsigned short* __restrict__ lo) {
  const size_t i4 = ((size_t)blockIdx.x * 256 + threadIdx.x) * 4;
  const float4 v = *(const float4*)(x + i4);
  ushort4 h, l;
  h.x = f2bf(v.x); l.x = f2bf(v.x - bf2f(h.x));
  h.y = f2bf(v.y); l.y = f2bf(v.y - bf2f(h.y));
  h.z = f2bf(v.z); l.z = f2bf(v.z - bf2f(h.z));
  h.w = f2bf(v.w); l.w = f2bf(v.w - bf2f(h.w));
  *(ushort4*)(hi + i4) = h;
  *(ushort4*)(lo + i4) = l;
}

__global__ __launch_bounds__(256) void k_cast_w(
    const float* __restrict__ w, unsigned short* __restrict__ wb) {
  const size_t i4 = ((size_t)blockIdx.x * 256 + threadIdx.x) * 4;
  const float4 v = *(const float4*)(w + i4);
  ushort4 h;
  h.x = f2bf(v.x); h.y = f2bf(v.y); h.z = f2bf(v.z); h.w = f2bf(v.w);
  *(ushort4*)(wb + i4) = h;
}

// ---------------------------------------------------------------------------
// Q/K GEMM, round-5 proven version (REVERT from 32x32 — conflict falsifier
// fired): 256x256, BK=32, 16x16x32 MFMA, 4-slot ring, register pipeline,
// 2-bit chunk-XOR involution (0 bank conflicts verified), barrier/2 steps.
// ---------------------------------------------------------------------------
__global__ __launch_bounds__(512) void k_qk_mfma8(
    const unsigned short* __restrict__ xhi, const unsigned short* __restrict__ xlo,
    const unsigned short* __restrict__ wb, const float* __restrict__ bias,
    float* __restrict__ qb, float* __restrict__ kb) {
  __shared__ __align__(16) unsigned short LA[4][8192];   // 4 slots x 256 rows x 32 K
  __shared__ __align__(16) unsigned short LB[4][8192];   // 64 KiB + 64 KiB
  const int bt0 = blockIdx.x * 256, j0 = blockIdx.y * 256;
  const int tid = threadIdx.x;
  const int lane = tid & 63, w = tid >> 6;
  const int wr = w >> 2, wc = w & 3;          // 2 M-groups x 4 N-groups
  const int col = lane & 15, quad = lane >> 4;
  const int qsz = (quad ^ ((col >> 1) & 3)) * 8;
  f32x4 acc[8][4] = {};
  v8s rA0[8], rB0[4], rA1[8], rB1[4];

  const int o0 = tid * 8;          // short offset of chunk 0 (dest, linear)
  const int row0 = tid >> 2;       // 0..127
  const int cb0 = (((tid & 3) ^ ((tid >> 3) & 3))) * 8;   // swizzled src shorts

#define QK_STAGE_A(kt)                                                        \
  {                                                                           \
    const unsigned short* ab_ = ((kt) < 32) ? xhi : xlo;                      \
    const int kc_ = ((kt) & 31) * 32;                                         \
    __builtin_amdgcn_global_load_lds(                                         \
        (const __attribute__((address_space(1))) void*)(ab_ +                 \
            (size_t)(bt0 + row0) * E_ + kc_ + cb0),                           \
        (__attribute__((address_space(3))) void*)&LA[(kt) & 3][o0], 16, 0, 0);\
    __builtin_amdgcn_global_load_lds(                                         \
        (const __attribute__((address_space(1))) void*)(ab_ +                 \
            (size_t)(bt0 + 128 + row0) * E_ + kc_ + cb0),                     \
        (__attribute__((address_space(3))) void*)&LA[(kt) & 3][o0 + 4096],    \
        16, 0, 0);                                                            \
  }
#define QK_STAGE_B(kt)                                                        \
  {                                                                           \
    const int kc_ = ((kt) & 31) * 32;                                         \
    __builtin_amdgcn_global_load_lds(                                         \
        (const __attribute__((address_space(1))) void*)(wb +                  \
            (size_t)(j0 + row0) * E_ + kc_ + cb0),                            \
        (__attribute__((address_space(3))) void*)&LB[(kt) & 3][o0], 16, 0, 0);\
    __builtin_amdgcn_global_load_lds(                                         \
        (const __attribute__((address_space(1))) void*)(wb +                  \
            (size_t)(j0 + 128 + row0) * E_ + kc_ + cb0),                      \
        (__attribute__((address_space(3))) void*)&LB[(kt) & 3][o0 + 4096],    \
        16, 0, 0);                                                            \
  }
#define QK_READ_FULL(RA, RB, kt)                                              \
  {                                                                           \
    _Pragma("unroll") for (int i_ = 0; i_ < 8; ++i_) {                        \
      const int row_ = wr * 128 + i_ * 16 + col;                              \
      RA[i_] = *(const v8s*)&LA[(kt) & 3][row_ * 32 + qsz];                   \
    }                                                                         \
    _Pragma("unroll") for (int j_ = 0; j_ < 4; ++j_) {                        \
      const int row_ = wc * 64 + j_ * 16 + col;                               \
      RB[j_] = *(const v8s*)&LB[(kt) & 3][row_ * 32 + qsz];                   \
    }                                                                         \
  }
#define QK_MFMA_ALL(RA, RB)                                                   \
  __builtin_amdgcn_s_setprio(1);                                              \
  _Pragma("unroll") for (int i_ = 0; i_ < 8; ++i_)                            \
    _Pragma("unroll") for (int j_ = 0; j_ < 4; ++j_)                          \
      acc[i_][j_] = __builtin_amdgcn_mfma_f32_16x16x32_bf16(                  \
          RA[i_], RB[j_], acc[i_][j_], 0, 0, 0);                              \
  __builtin_amdgcn_s_setprio(0);

  QK_STAGE_A(0); QK_STAGE_B(0);
  QK_STAGE_A(1); QK_STAGE_B(1);
  QK_STAGE_A(2); QK_STAGE_B(2);
  QK_STAGE_A(3); QK_STAGE_B(3);
  asm volatile("s_waitcnt vmcnt(4)" ::: "memory");
  asm volatile("s_barrier" ::: "memory");
  QK_READ_FULL(rA0, rB0, 0);
  asm volatile("s_waitcnt lgkmcnt(0)" ::: "memory");

#pragma unroll 1
  for (int s = 0; s < 64; s += 2) {
    if (s < 63) QK_READ_FULL(rA1, rB1, s + 1);
    if (s + 4 < 64) { QK_STAGE_A(s + 4); QK_STAGE_B(s + 4); }
    QK_MFMA_ALL(rA0, rB0);
    if (s + 2 < 64) QK_READ_FULL(rA0, rB0, s + 2);
    if (s + 5 < 64) { QK_STAGE_A(s + 5); QK_STAGE_B(s + 5); }
    QK_MFMA_ALL(rA1, rB1);
    if (s <= 55) {
      asm volatile("s_waitcnt vmcnt(4)" ::: "memory");
    } else if (s <= 59) {
      asm volatile("s_waitcnt vmcnt(0)" ::: "memory");
    }
    asm volatile("s_barrier" ::: "memory");
  }

#undef QK_MFMA_ALL
#undef QK_READ_FULL
#undef QK_STAGE_B
#undef QK_STAGE_A

#pragma unroll
  for (int j = 0; j < 4; ++j) {
    const int n = j0 + wc * 64 + j * 16 + col;
    const int sec = n >> 10, nn = n & 1023, h = nn >> 6, dd = nn & 63;
    float* dst = (sec == 0) ? qb : kb;
    const float bv = bias[n];
#pragma unroll
    for (int i = 0; i < 8; ++i) {
      const int mbase = bt0 + wr * 128 + i * 16 + quad * 4;
#pragma unroll
      for (int r = 0; r < 4; ++r) {
        const int m = mbase + r;
        const int b = m >> 12, t = m & (T_ - 1);
        dst[((size_t)(b * H_ + h) * T_ + t) * D_ + dd] = acc[i][j][r] + bv;
      }
    }
  }
}

// ---------------------------------------------------------------------------
// V / Out GEMM, round-14: proven qk ring structure at 128x256 tile so that
// grid (64,4) = 256 blocks fills all CUs. BK=32, 4-slot ring, gload_lds
// width-16, chunk-XOR involution (row bases = 0 mod 4 -> same key as qk),
// counted vmcnt(3) (3 loads/stage). Single bf16 A (hi-only for V, obf for
// Out). mode 0: bf16 scatter to vbf layout; mode 1: fp32 linear to out.
// K = 1024 -> 32 steps. 8 waves (2M x 4N), per-wave 64x64 tile.
// LDS = 4*(8KB A + 16KB B) = 96 KB -> 1 block/CU.
// ---------------------------------------------------------------------------
__global__ __launch_bounds__(512) void k_nko_mfma8(
    const unsigned short* __restrict__ Aa, const unsigned short* __restrict__ Bw,
    const float* __restrict__ bias, unsigned short* __restrict__ obf16,
    float* __restrict__ ofp32, int mode) {
  __shared__ __align__(16) unsigned short LA[4][4096];   // 128 rows x 32 K
  __shared__ __align__(16) unsigned short LB[4][8192];   // 256 rows x 32 K
  const int bt0 = blockIdx.x * 128, j0 = blockIdx.y * 256;
  const int tid = threadIdx.x;
  const int lane = tid & 63, w = tid >> 6;
  const int wr = w >> 2, wc = w & 3;          // 2 M-groups x 4 N-groups
  const int col = lane & 15, quad = lane >> 4;
  const int qsz = (quad ^ ((col >> 1) & 3)) * 8;
  f32x4 acc[4][4] = {};
  v8s rA0[4], rB0[4], rA1[4], rB1[4];

  const int o0 = tid * 8;          // dest short offset (linear)
  const int row0 = tid >> 2;       // 0..127
  const int cb0 = (((tid & 3) ^ ((tid >> 3) & 3))) * 8;   // swizzled src shorts

#define NK_STAGE(kt)                                                          \
  {                                                                           \
    const int kc_ = (kt) * 32;                                                \
    __builtin_amdgcn_global_load_lds(                                         \
        (const __attribute__((address_space(1))) void*)(Aa +                  \
            (size_t)(bt0 + row0) * E_ + kc_ + cb0),                           \
        (__attribute__((address_space(3))) void*)&LA[(kt) & 3][o0], 16, 0, 0);\
    __builtin_amdgcn_global_load_lds(                                         \
        (const __attribute__((address_space(1))) void*)(Bw +                  \
            (size_t)(j0 + row0) * E_ + kc_ + cb0),                            \
        (__attribute__((address_space(3))) void*)&LB[(kt) & 3][o0], 16, 0, 0);\
    __builtin_amdgcn_global_load_lds(                                         \
        (const __attribute__((address_space(1))) void*)(Bw +                  \
            (size_t)(j0 + 128 + row0) * E_ + kc_ + cb0),                      \
        (__attribute__((address_space(3))) void*)&LB[(kt) & 3][o0 + 4096],    \
        16, 0, 0);                                                            \
  }
#define NK_READ(RA, RB, kt)                                                   \
  {                                                                           \
    _Pragma("unroll") for (int i_ = 0; i_ < 4; ++i_) {                        \
      const int row_ = wr * 64 + i_ * 16 + col;                               \
      RA[i_] = *(const v8s*)&LA[(kt) & 3][row_ * 32 + qsz];                   \
    }                                                                         \
    _Pragma("unroll") for (int j_ = 0; j_ < 4; ++j_) {                        \
      const int row_ = wc * 64 + j_ * 16 + col;                               \
      RB[j_] = *(const v8s*)&LB[(kt) & 3][row_ * 32 + qsz];                   \
    }                                                                         \
  }
#define NK_MFMA(RA, RB)                                                       \
  __builtin_amdgcn_s_setprio(1);                                              \
  _Pragma("unroll") for (int i_ = 0; i_ < 4; ++i_)                            \
    _Pragma("unroll") for (int j_ = 0; j_ < 4; ++j_)                          \
      acc[i_][j_] = __builtin_amdgcn_mfma_f32_16x16x32_bf16(                  \
          RA[i_], RB[j_], acc[i_][j_], 0, 0, 0);                              \
  __builtin_amdgcn_s_setprio(0);

  NK_STAGE(0); NK_STAGE(1); NK_STAGE(2); NK_STAGE(3);
  asm volatile("s_waitcnt vmcnt(3)" ::: "memory");
  asm volatile("s_barrier" ::: "memory");
  NK_READ(rA0, rB0, 0);
  asm volatile("s_waitcnt lgkmcnt(0)" ::: "memory");

#pragma unroll 1
  for (int s = 0; s < 28; s += 2) {
    NK_READ(rA1, rB1, s + 1);
    NK_STAGE(s + 4);
    NK_MFMA(rA0, rB0);
    NK_READ(rA0, rB0, s + 2);
    NK_STAGE(s + 5);
    NK_MFMA(rA1, rB1);
    asm volatile("s_waitcnt vmcnt(3)" ::: "memory");
    asm volatile("s_barrier" ::: "memory");
  }
  // s = 28: no stages remain; drain last tile (31)
  NK_READ(rA1, rB1, 29);
  NK_MFMA(rA0, rB0);
  NK_READ(rA0, rB0, 30);
  NK_MFMA(rA1, rB1);
  asm volatile("s_waitcnt vmcnt(0)" ::: "memory");
  asm volatile("s_barrier" ::: "memory");
  // s = 30
  NK_READ(rA1, rB1, 31);
  NK_MFMA(rA0, rB0);
  NK_MFMA(rA1, rB1);

#undef NK_MFMA
#undef NK_READ
#undef NK_STAGE

#pragma unroll
  for (int j = 0; j < 4; ++j) {
    const int n = j0 + wc * 64 + j * 16 + col;   // 0..1023
    const float bv = bias[n];
    const int h = n >> 6, dd = n & 63;
#pragma unroll
    for (int i = 0; i < 4; ++i) {
      const int mbase = bt0 + wr * 64 + i * 16 + quad * 4;
#pragma unroll
      for (int r = 0; r < 4; ++r) {
        const int m = mbase + r;
        const float val = acc[i][j][r] + bv;
        if (mode == 0) {
          const int b = m >> 12, t = m & (T_ - 1);
          obf16[((size_t)(b * H_ + h) * T_ + t) * D_ + dd] = f2bf(val);
        } else {
          ofp32[(size_t)m * E_ + n] = val;
        }
      }
    }
  }
}

// ---------------------------------------------------------------------------
// Features via MFMA (unchanged)
// ---------------------------------------------------------------------------
__global__ __launch_bounds__(256) void k_feat_mfma(
    const float* __restrict__ xin, const float* __restrict__ poly_w,
    const float* __restrict__ omega, const float* __restrict__ qnod,
    const float* __restrict__ qwt, unsigned short* __restrict__ pqb,
    unsigned short* __restrict__ fqb) {
  __shared__ __align__(16) unsigned short XH[128 * 72];
  __shared__ __align__(16) unsigned short XL[128 * 72];
  __shared__ __align__(16) unsigned short Bs[80 * 72];
  const int bh = blockIdx.x >> 5;
  const int t0 = (blockIdx.x & 31) * 128;
  const int h = bh & (H_ - 1);
  const int tid = threadIdx.x, lane = tid & 63, w = tid >> 6;
  const int col = lane & 15, quad = lane >> 4;
  const size_t rowB = (size_t)bh * T_ + t0;

  const float s0 = qnod[0];
  const float sq2 = sqrtf(fmaxf(2.f * s0, 0.f));
  const float scale = sqrtf(fmaxf(qwt[0], 0.f)) * 0.3535533905932738f;

  for (int rr = 0; rr < 32; ++rr) {
    const int t = w * 32 + rr;
    const float xv = xin[(rowB + t) * D_ + lane];
    float ss = xv * xv;
#pragma unroll
    for (int off = 32; off > 0; off >>= 1) ss += __shfl_xor(ss, off);
    const float rn = 1.0f / fmaxf(sqrtf(ss), 1e-12f);
    const float xn = xv * rn;
    const unsigned short hi = f2bf(xn);
    XH[t * 72 + lane] = hi;
    XL[t * 72 + lane] = f2bf(xn - bf2f(hi));
  }
  {
    const int base = tid * 16;
#pragma unroll
    for (int j4 = 0; j4 < 4; ++j4) {
      const int idx = base + j4 * 4;
      const int d = idx >> 6, p = idx & 63;
      const float4 v = *(const float4*)(poly_w + (size_t)h * 4096 + idx);
      Bs[(p + 0) * 72 + d] = f2bf(v.x);
      Bs[(p + 1) * 72 + d] = f2bf(v.y);
      Bs[(p + 2) * 72 + d] = f2bf(v.z);
      Bs[(p + 3) * 72 + d] = f2bf(v.w);
    }
    if (tid < 128) {
      const int idx = tid * 4;
      const int d = idx >> 3, m0 = idx & 7;
      const float4 v = *(const float4*)(omega + (size_t)h * 512 + idx);
      Bs[(64 + m0 + 0) * 72 + d] = f2bf(v.x);
      Bs[(64 + m0 + 1) * 72 + d] = f2bf(v.y);
      Bs[(64 + m0 + 2) * 72 + d] = f2bf(v.z);
      Bs[(64 + m0 + 3) * 72 + d] = f2bf(v.w);
    }
  }
  __syncthreads();
  f32x4 acc[2][5] = {};
#pragma unroll
  for (int kk = 0; kk < 2; ++kk) {
    v8s ah[2], al[2];
#pragma unroll
    for (int i = 0; i < 2; ++i) {
      const int mo = ((2 * w + i) * 16 + col) * 72 + kk * 32 + quad * 8;
      ah[i] = *(const v8s*)&XH[mo];
      al[i] = *(const v8s*)&XL[mo];
    }
#pragma unroll
    for (int nt = 0; nt < 5; ++nt) {
      const v8s bb = *(const v8s*)&Bs[(nt * 16 + col) * 72 + kk * 32 + quad * 8];
#pragma unroll
      for (int i = 0; i < 2; ++i) {
        acc[i][nt] = __builtin_amdgcn_mfma_f32_16x16x32_bf16(ah[i], bb, acc[i][nt], 0, 0, 0);
        acc[i][nt] = __builtin_amdgcn_mfma_f32_16x16x32_bf16(al[i], bb, acc[i][nt], 0, 0, 0);
      }
    }
  }
#pragma unroll
  for (int i = 0; i < 2; ++i) {
#pragma unroll
    for (int r = 0; r < 4; ++r) {
      const int t = (2 * w + i) * 16 + quad * 4 + r;
#pragma unroll
      for (int nt = 0; nt < 4; ++nt) {
        const float c = acc[i][nt][r];
        pqb[(rowB + t) * P_ + nt * 16 + col] = f2bf(c * c * 0.125f);
      }
      if (col < 8) {
        const float c = acc[i][4][r];
        const float z = fminf(fmaxf(c * sq2 - s0, -20.f), 20.f);
        fqb[(rowB + t) * M_ + col] = f2bf(expf(z) * scale);
      }
    }
  }
}

// ---------------------------------------------------------------------------
// Phase A via MFMA (unchanged)
// ---------------------------------------------------------------------------
__global__ __launch_bounds__(512) void k_phaseA(
    const unsigned short* __restrict__ pkb, const unsigned short* __restrict__ fkb,
    const unsigned short* __restrict__ vbf, unsigned short* __restrict__ kvch,
    float* __restrict__ ksum) {
  __shared__ __align__(16) unsigned short VT[64 * 72];
  __shared__ __align__(16) unsigned short pkT[64 * 72];
  __shared__ __align__(16) unsigned short fkT[8 * 72];
  const int bh = blockIdx.x & (BH_ - 1);
  const int c = blockIdx.x >> 5;
  const size_t rowC = (size_t)bh * T_ + (size_t)c * CH_;
  const int tid = threadIdx.x, lane = tid & 63, w = tid >> 6;
  const int col = lane & 15, quad = lane >> 4;
  const int nb = w * 64;
  f32x4 acc[4][4] = {};
  float ks[4] = {0.f, 0.f, 0.f, 0.f};

  for (int st = 0; st < 4; ++st) {
    const size_t t0 = rowC + st * 64;
    __syncthreads();
#pragma unroll
    for (int ps = 0; ps < 2; ++ps) {
      const int idx = ps * 512 + tid;
      const int t = idx >> 4, dg = (idx & 15) * 4;
      const ushort4 v = *(const ushort4*)(vbf + (t0 + t) * D_ + dg);
      VT[(dg + 0) * 72 + t] = v.x;
      VT[(dg + 1) * 72 + t] = v.y;
      VT[(dg + 2) * 72 + t] = v.z;
      VT[(dg + 3) * 72 + t] = v.w;
    }
    {
      const int t = tid >> 3, pg = (tid & 7) * 8;
      const v8s pv = *(const v8s*)(pkb + (t0 + t) * P_ + pg);
#pragma unroll
      for (int j = 0; j < 8; ++j) pkT[(pg + j) * 72 + t] = (unsigned short)pv[j];
    }
    if (tid < 64) {
      const v8s fv = *(const v8s*)(fkb + (t0 + tid) * M_);
#pragma unroll
      for (int j = 0; j < 8; ++j) fkT[j * 72 + tid] = (unsigned short)fv[j];
    }
    __syncthreads();
#pragma unroll
    for (int kk = 0; kk < 2; ++kk) {
      v8s a[4];
#pragma unroll
      for (int mt = 0; mt < 4; ++mt)
        a[mt] = *(const v8s*)&VT[(mt * 16 + col) * 72 + kk * 32 + quad * 8];
#pragma unroll
      for (int nt = 0; nt < 4; ++nt) {
        const int pm = nb + nt * 16 + col;
        const int p = pm >> 3, m8 = pm & 7;
        const v8s pkv = *(const v8s*)&pkT[p * 72 + kk * 32 + quad * 8];
        const v8s fkv = *(const v8s*)&fkT[m8 * 72 + kk * 32 + quad * 8];
        v8s bfrag;
        float kss = 0.f;
#pragma unroll
        for (int j = 0; j < 8; ++j) {
          const float v = bf2f((unsigned short)pkv[j]) * bf2f((unsigned short)fkv[j]);
          kss += v;
          bfrag[j] = (short)f2bf(v);
        }
        ks[nt] += kss;
#pragma unroll
        for (int mt = 0; mt < 4; ++mt)
          acc[mt][nt] = __builtin_amdgcn_mfma_f32_16x16x32_bf16(a[mt], bfrag, acc[mt][nt], 0, 0, 0);
      }
    }
  }
  const size_t base = (size_t)(c * BH_ + bh) * D_ * F_;
#pragma unroll
  for (int nt = 0; nt < 4; ++nt) {
    const int pm = nb + nt * 16 + col;
#pragma unroll
    for (int mt = 0; mt < 4; ++mt) {
#pragma unroll
      for (int r = 0; r < 4; ++r) {
        const int d = mt * 16 + quad * 4 + r;
        kvch[base + (size_t)d * F_ + pm] = f2bf(acc[mt][nt][r]);
      }
    }
    float kv_ = ks[nt];
    kv_ += __shfl_xor(kv_, 16);
    kv_ += __shfl_xor(kv_, 32);
    if (quad == 0) ksum[(size_t)(c * BH_ + bh) * F_ + pm] = kv_;
  }
}

// ---------------------------------------------------------------------------
__global__ __launch_bounds__(256) void k_scan_kv(unsigned short* __restrict__ kvch) {
  const size_t s = (size_t)blockIdx.x * 256 + threadIdx.x;
  const size_t stride = (size_t)BH_ * D_ * F_;
  unsigned short v[NC_];
#pragma unroll
  for (int c = 0; c < NC_; ++c) v[c] = kvch[(size_t)c * stride + s];
  float run = 0.f;
#pragma unroll
  for (int c = 0; c < NC_; ++c) {
    const float t = bf2f(v[c]);
    kvch[(size_t)c * stride + s] = f2bf(run);
    run += t;
  }
}

__global__ __launch_bounds__(256) void k_scan_ks(float* __restrict__ ksum) {
  const int s = blockIdx.x * 256 + threadIdx.x;
  const int stride = BH_ * F_;
  float v[NC_];
#pragma unroll
  for (int c = 0; c < NC_; ++c) v[c] = ksum[c * stride + s];
  float run = 0.f;
#pragma unroll
  for (int c = 0; c < NC_; ++c) {
    const float t = v[c];
    ksum[c * stride + s] = run;
    run += t;
  }
}

// ---------------------------------------------------------------------------
// Fused scores+intra (round-11 version: pk/fk LDS staging + 3rd-MFMA fusion)
// ---------------------------------------------------------------------------
__global__ __launch_bounds__(256) void k_sintra(
    const unsigned short* __restrict__ pqb, const unsigned short* __restrict__ fqb,
    const unsigned short* __restrict__ pkb, const unsigned short* __restrict__ fkb,
    const unsigned short* __restrict__ vbf, float* __restrict__ obuf,
    float* __restrict__ nrmbuf) {
  __shared__ __align__(16) unsigned short S_lds[128 * 136];
  __shared__ __align__(16) unsigned short VT[64 * 136];
  __shared__ __align__(16) unsigned short pkT[128 * 72];
  __shared__ __align__(16) unsigned short fkT[128 * 8];
  const int bh = blockIdx.x & (BH_ - 1);
  const int tq = blockIdx.x >> 5;
  const int c = tq >> 1, h2 = tq & 1;
  const size_t rowT = (size_t)bh * T_ + (size_t)tq * 128;
  const size_t rowC = (size_t)bh * T_ + (size_t)c * CH_;
  const int tid = threadIdx.x, lane = tid & 63, w = tid >> 6;
  const int col = lane & 15, quad = lane >> 4;

  const v8s vzero = {};
  v8s bq[2][2], bqf[2];
#pragma unroll
  for (int i = 0; i < 2; ++i) {
    const size_t qrow = rowT + (2 * w + i) * 16 + col;
    bq[i][0] = *(const v8s*)(pqb + qrow * P_ + quad * 8);
    bq[i][1] = *(const v8s*)(pqb + qrow * P_ + 32 + quad * 8);
    const v8s fv = *(const v8s*)(fqb + qrow * M_);
    bqf[i] = (quad == 0) ? fv : vzero;
  }
  f32x4 acc[2][4] = {};
  float rs[2] = {0.f, 0.f};

  const int vd = tid & 63, vg = tid >> 6;

  for (int sl = 0; sl <= h2; ++sl) {
    const size_t rowS = rowC + (size_t)sl * 128;
    __syncthreads();
#pragma unroll
    for (int c4 = 0; c4 < 4; ++c4) {
      const int g = c4 * 256 + tid;
      const int row = g >> 3, ch = g & 7;
      *(v8s*)&pkT[row * 72 + ch * 8] =
          *(const v8s*)(pkb + (rowS + row) * P_ + ch * 8);
    }
    if (tid < 128)
      *(v8s*)&fkT[tid * 8] = *(const v8s*)(fkb + (rowS + tid) * M_);
#pragma unroll
    for (int j8 = 0; j8 < 4; ++j8) {
      const int s0 = vg * 32 + j8 * 8;
      v8s pv;
#pragma unroll
      for (int k = 0; k < 8; ++k)
        pv[k] = (short)vbf[(rowS + s0 + k) * D_ + vd];
      *(v8s*)&VT[vd * 136 + s0] = pv;
    }
    __syncthreads();
    for (int si = 0; si < 8; ++si) {
      const int srow = si * 16 + col;
      const v8s a0 = *(const v8s*)&pkT[srow * 72 + quad * 8];
      const v8s a1 = *(const v8s*)&pkT[srow * 72 + 32 + quad * 8];
      const v8s af = (quad == 0) ? *(const v8s*)&fkT[srow * 8] : vzero;
#pragma unroll
      for (int i = 0; i < 2; ++i) {
        const int tt = 2 * w + i;
        const int t_rel = h2 * 128 + tt * 16 + col;
        f32x4 sp = {};
        sp = __builtin_amdgcn_mfma_f32_16x16x32_bf16(a0, bq[i][0], sp, 0, 0, 0);
        sp = __builtin_amdgcn_mfma_f32_16x16x32_bf16(a1, bq[i][1], sp, 0, 0, 0);
        f32x4 spf = {};
        spf = __builtin_amdgcn_mfma_f32_16x16x32_bf16(af, bqf[i], spf, 0, 0, 0);
        ushort4 pk4;
        float partial = 0.f;
#pragma unroll
        for (int r = 0; r < 4; ++r) {
          const int s_in = si * 16 + quad * 4 + r;
          float val = sp[r] * spf[r];
          const int s_rel = sl * 128 + s_in;
          val = (s_rel <= t_rel) ? val : 0.f;
          partial += val;
          ((unsigned short*)&pk4)[r] = f2bf(val);
        }
        rs[i] += partial;
        *(ushort4*)&S_lds[(tt * 16 + col) * 136 + si * 16 + quad * 4] = pk4;
      }
    }
    __syncthreads();
#pragma unroll
    for (int i = 0; i < 2; ++i) {
      const int tt = 2 * w + i;
#pragma unroll
      for (int kk = 0; kk < 4; ++kk) {
        const v8s sa = *(const v8s*)&S_lds[(tt * 16 + col) * 136 + kk * 32 + quad * 8];
#pragma unroll
        for (int dt = 0; dt < 4; ++dt) {
          const v8s vb8 = *(const v8s*)&VT[(dt * 16 + col) * 136 + kk * 32 + quad * 8];
          acc[i][dt] = __builtin_amdgcn_mfma_f32_16x16x32_bf16(sa, vb8, acc[i][dt], 0, 0, 0);
        }
      }
    }
  }
#pragma unroll
  for (int i = 0; i < 2; ++i) {
#pragma unroll
    for (int dt = 0; dt < 4; ++dt) {
#pragma unroll
      for (int r = 0; r < 4; ++r) {
        const int t = (2 * w + i) * 16 + quad * 4 + r;
        obuf[(rowT + t) * D_ + dt * 16 + col] = acc[i][dt][r];
      }
    }
    rs[i] += __shfl_xor(rs[i], 16);
    rs[i] += __shfl_xor(rs[i], 32);
  }
  if (lane < 16) {
    const size_t nbase = (size_t)(c * BH_ + bh) * CH_ + h2 * 128;
    nrmbuf[nbase + (2 * w + 0) * 16 + lane] = rs[0];
    nrmbuf[nbase + (2 * w + 1) * 16 + lane] = rs[1];
  }
}

// ---------------------------------------------------------------------------
// Hist via MFMA (unchanged)
// ---------------------------------------------------------------------------
__global__ __launch_bounds__(256) void k_hist(
    const unsigned short* __restrict__ pqb, const unsigned short* __restrict__ fqb,
    const unsigned short* __restrict__ kvch, const float* __restrict__ ksum,
    const float* __restrict__ nrmbuf, const float* __restrict__ obuf,
    unsigned short* __restrict__ obf) {
  __shared__ __align__(16) unsigned short QF_lds[128 * 72];
  __shared__ __align__(16) unsigned short KV_lds[64 * 72];
  __shared__ float kp_lds[F_];
  __shared__ float nhs[128];
  const int half = blockIdx.x & 1;
  const int bh = (blockIdx.x >> 1) & (BH_ - 1);
  const int c = blockIdx.x >> 6;
  const int b = bh >> 4, h = bh & (H_ - 1);
  const int tid = threadIdx.x, lane = tid & 63, w = tid >> 6;
  const int col = lane & 15, quad = lane >> 4;
  const size_t rowQ = (size_t)bh * T_ + (size_t)c * CH_ + half * 128;
  const size_t kvbase = (size_t)(c * BH_ + bh) * D_ * F_;

  const int tr = tid >> 1, side = tid & 1;
  float fqr[8];
  {
    const v8s fv = *(const v8s*)(fqb + (rowQ + tr) * M_);
#pragma unroll
    for (int j = 0; j < 8; ++j) fqr[j] = bf2f((unsigned short)fv[j]);
    if (tid < 128)
      *(float4*)(&kp_lds[tid * 4]) =
          *(const float4*)(ksum + (size_t)(c * BH_ + bh) * F_ + tid * 4);
  }
  f32x4 acc[2][4] = {};
  float nh_part = 0.f;
  const int gr = tid & 7, d0 = tid >> 3;

  for (int pmt = 0; pmt < 8; ++pmt) {
    __syncthreads();
#pragma unroll
    for (int pp = 0; pp < 2; ++pp) {
      const int d = d0 + pp * 32;
      *(v8s*)&KV_lds[d * 72 + gr * 8] =
          *(const v8s*)(kvch + kvbase + (size_t)d * F_ + pmt * 64 + gr * 8);
    }
    {
      const v8s pq8 = *(const v8s*)(pqb + (rowQ + tr) * P_ + pmt * 8);
#pragma unroll
      for (int pp = 0; pp < 4; ++pp) {
        const int pl = side * 4 + pp;
        const float pqf = bf2f((unsigned short)pq8[pl]);
        const int kb_ = (pmt * 8 + pl) * 8;
        v8s o;
#pragma unroll
        for (int j = 0; j < 8; ++j) {
          const float v = pqf * fqr[j];
          nh_part += v * kp_lds[kb_ + j];
          o[j] = (short)f2bf(v);
        }
        *(v8s*)&QF_lds[tr * 72 + pl * 8] = o;
      }
    }
    __syncthreads();
#pragma unroll
    for (int kk = 0; kk < 2; ++kk) {
      v8s a[2], bb[4];
#pragma unroll
      for (int i = 0; i < 2; ++i)
        a[i] = *(const v8s*)&QF_lds[((2 * w + i) * 16 + col) * 72 + kk * 32 + quad * 8];
#pragma unroll
      for (int j = 0; j < 4; ++j)
        bb[j] = *(const v8s*)&KV_lds[(j * 16 + col) * 72 + kk * 32 + quad * 8];
#pragma unroll
      for (int i = 0; i < 2; ++i)
#pragma unroll
        for (int j = 0; j < 4; ++j)
          acc[i][j] = __builtin_amdgcn_mfma_f32_16x16x32_bf16(a[i], bb[j], acc[i][j], 0, 0, 0);
    }
  }
  {
    const float nh = nh_part + __shfl_xor(nh_part, 1);
    if (!(tid & 1)) nhs[tr] = nh;
  }
  __syncthreads();
  const size_t nbase = (size_t)(c * BH_ + bh) * CH_ + half * 128;
#pragma unroll
  for (int i = 0; i < 2; ++i) {
#pragma unroll
    for (int r = 0; r < 4; ++r) {
      const int t = (2 * w + i) * 16 + quad * 4 + r;
      const float nrm = nhs[t] + nrmbuf[nbase + t] + 1e-6f;
      const float rcp = 1.0f / nrm;
#pragma unroll
      for (int j = 0; j < 4; ++j) {
        const int d = j * 16 + col;
        const float val = (obuf[(rowQ + t) * D_ + d] + acc[i][j][r]) * rcp;
        obf[(size_t)(b * T_ + c * CH_ + half * 128 + t) * E_ + h * 64 + d] = f2bf(val);
      }
    }
  }
}

// ---------------------------------------------------------------------------
extern "C" void kernel_launch(void* const* d_in, const int* in_sizes, int n_in,
                              void* d_out, int out_size, void* d_ws, size_t ws_size,
                              hipStream_t stream) {
  (void)in_sizes; (void)n_in; (void)out_size; (void)ws_size;
  const float* x      = (const float*)d_in[0];
  const float* qkv_w  = (const float*)d_in[1];
  const float* qkv_b  = (const float*)d_in[2];
  const float* out_w  = (const float*)d_in[3];
  const float* out_b  = (const float*)d_in[4];
  const float* omega  = (const float*)d_in[5];
  const float* poly_w = (const float*)d_in[6];
  const float* qnod   = (const float*)d_in[7];
  const float* qwt    = (const float*)d_in[8];
  float* ws = (float*)d_ws;
  float* qb   = ws + OFF_Q;
  float* kb   = ws + OFF_K;
  unsigned short* vbf = (unsigned short*)(ws + OFF_V);
  unsigned short* fqb = (unsigned short*)(ws + OFF_FQ);
  unsigned short* fkb = (unsigned short*)(ws + OFF_FK);
  float* ksb  = ws + OFF_KS;
  float* nrmb = ws + OFF_NRM;
  float* ob   = ws + OFF_O;
  unsigned short* kvb = (unsigned short*)(ws + OFF_KV);
  unsigned short* pqb = kvb + 16777216;
  unsigned short* pkb = pqb + SZ_BHTD;
  unsigned short* xhi  = kvb;
  unsigned short* xlo  = kvb + SZ_BHTD;
  unsigned short* wqkv = kvb + 2 * SZ_BHTD;
  unsigned short* obf   = (unsigned short*)kb;
  unsigned short* woutb = (unsigned short*)(ws + OFF_V);  // over dead v (post-sintra)
  float* outp = (float*)d_out;

  hipLaunchKernelGGL(k_split_x, dim3(8192), dim3(256), 0, stream, x, xhi, xlo);
  hipLaunchKernelGGL(k_cast_w, dim3(3072), dim3(256), 0, stream, qkv_w, wqkv);
  hipLaunchKernelGGL(k_qk_mfma8, dim3(BT_ / 256, 8), dim3(512), 0, stream,
                     xhi, xlo, wqkv, qkv_b, qb, kb);
  hipLaunchKernelGGL(k_nko_mfma8, dim3(BT_ / 128, 4), dim3(512), 0, stream,
                     xhi, wqkv + (size_t)2048 * E_, qkv_b + 2048, vbf,
                     (float*)nullptr, 0);
  hipLaunchKernelGGL(k_feat_mfma, dim3(1024), dim3(256), 0, stream,
                     qb, poly_w, omega, qnod, qwt, pqb, fqb);
  hipLaunchKernelGGL(k_feat_mfma, dim3(1024), dim3(256), 0, stream,
                     kb, poly_w, omega, qnod, qwt, pkb, fkb);
  hipLaunchKernelGGL(k_phaseA, dim3(NC_ * BH_), dim3(512), 0, stream,
                     pkb, fkb, vbf, kvb, ksb);
  hipLaunchKernelGGL(k_scan_kv, dim3(4096), dim3(256), 0, stream, kvb);
  hipLaunchKernelGGL(k_scan_ks, dim3(64), dim3(256), 0, stream, ksb);
  hipLaunchKernelGGL(k_sintra, dim3(BH_ * 32), dim3(256), 0, stream,
                     pqb, fqb, pkb, fkb, vbf, ob, nrmb);
  hipLaunchKernelGGL(k_cast_w, dim3(1024), dim3(256), 0, stream, out_w, woutb);
  hipLaunchKernelGGL(k_hist, dim3(NC_ * BH_ * 2), dim3(256), 0, stream,
                     pqb, fqb, kvb, ksb, nrmb, ob, obf);
  hipLaunchKernelGGL(k_nko_mfma8, dim3(BT_ / 128, 4), dim3(512), 0, stream,
                     obf, woutb, out_b, (unsigned short*)nullptr, outp, 1);
}

// Round 9
// 397.458 us; speedup vs baseline: 1.0877x; 1.0699x over previous
//
#include <hip/hip_runtime.h>
#include <math.h>

#define B_ 2
#define T_ 4096
#define E_ 1024
#define H_ 16
#define D_ 64
#define P_ 64
#define M_ 8
#define CH_ 256
#define NC_ 16
#define F_ 512
#define BH_ 32
#define BT_ 8192

// ---- workspace layout ----
static constexpr size_t SZ_BHTD = (size_t)B_ * H_ * T_ * D_;     // 8,388,608
static constexpr size_t SZ_PRF  = (size_t)B_ * H_ * T_ * M_;     // 1,048,576
static constexpr size_t SZ_KS   = (size_t)NC_ * BH_ * F_;        // 262,144
static constexpr size_t SZ_NRM  = (size_t)NC_ * BH_ * CH_;       // 131,072
static constexpr size_t SZ_KV_E = 33554432;                      // bf16 region

static constexpr size_t OFF_Q   = 0;
static constexpr size_t OFF_K   = OFF_Q + SZ_BHTD;
static constexpr size_t OFF_V   = OFF_K + SZ_BHTD;    // v bf16 (half used); woutb overlay later
static constexpr size_t OFF_FQ  = OFF_V + SZ_BHTD;
static constexpr size_t OFF_FK  = OFF_FQ + SZ_PRF;
static constexpr size_t OFF_KS  = OFF_FK + SZ_PRF;
static constexpr size_t OFF_NRM = OFF_KS + SZ_KS;
static constexpr size_t OFF_O   = OFF_NRM + SZ_NRM;
static constexpr size_t OFF_KV  = OFF_O + SZ_BHTD;
// total = OFF_KV*4 + SZ_KV_E*2 = 211,288,064 B (~201.5 MiB)

__device__ __forceinline__ float bf2f(unsigned short u) {
  union { unsigned u32; float f; } x; x.u32 = ((unsigned)u) << 16; return x.f;
}
__device__ __forceinline__ unsigned short f2bf(float f) {
  union { float f; unsigned u; } x; x.f = f;
  unsigned r = x.u + 0x7fffu + ((x.u >> 16) & 1u);
  return (unsigned short)(r >> 16);
}

typedef short v8s __attribute__((ext_vector_type(8)));
typedef float f32x4 __attribute__((ext_vector_type(4)));
#define LDSA 72   // GEMM LDS stride (bf16) for the remaining 128-tile GEMMs

// ---------------------------------------------------------------------------
// round-15: hi-only x (lo-pass dropped from qk — see V precedent; xlo dead)
__global__ __launch_bounds__(256) void k_split_x(
    const float* __restrict__ x, unsigned short* __restrict__ hi,
    unsigned short* __restrict__ lo) {
  (void)lo;
  const size_t i4 = ((size_t)blockIdx.x * 256 + threadIdx.x) * 4;
  const float4 v = *(const float4*)(x + i4);
  ushort4 h;
  h.x = f2bf(v.x); h.y = f2bf(v.y); h.z = f2bf(v.z); h.w = f2bf(v.w);
  *(ushort4*)(hi + i4) = h;
}

__global__ __launch_bounds__(256) void k_cast_w(
    const float* __restrict__ w, unsigned short* __restrict__ wb) {
  const size_t i4 = ((size_t)blockIdx.x * 256 + threadIdx.x) * 4;
  const float4 v = *(const float4*)(w + i4);
  ushort4 h;
  h.x = f2bf(v.x); h.y = f2bf(v.y); h.z = f2bf(v.z); h.w = f2bf(v.w);
  *(ushort4*)(wb + i4) = h;
}

// ---------------------------------------------------------------------------
// Q/K GEMM, round-15: round-5 proven structure, hi-only A (lo-pass dropped).
// K = 1024 -> 32 steps. 256x256, BK=32, 16x16x32 MFMA, 4-slot ring, register
// pipeline, 2-bit chunk-XOR involution (0 bank conflicts verified),
// barrier per 2 K-steps, counted vmcnt(4). grid (32,8), block 512.
// ---------------------------------------------------------------------------
__global__ __launch_bounds__(512) void k_qk_mfma8(
    const unsigned short* __restrict__ xhi, const unsigned short* __restrict__ xlo,
    const unsigned short* __restrict__ wb, const float* __restrict__ bias,
    float* __restrict__ qb, float* __restrict__ kb) {
  (void)xlo;
  __shared__ __align__(16) unsigned short LA[4][8192];   // 4 slots x 256 rows x 32 K
  __shared__ __align__(16) unsigned short LB[4][8192];   // 64 KiB + 64 KiB
  const int bt0 = blockIdx.x * 256, j0 = blockIdx.y * 256;
  const int tid = threadIdx.x;
  const int lane = tid & 63, w = tid >> 6;
  const int wr = w >> 2, wc = w & 3;          // 2 M-groups x 4 N-groups
  const int col = lane & 15, quad = lane >> 4;
  const int qsz = (quad ^ ((col >> 1) & 3)) * 8;
  f32x4 acc[8][4] = {};
  v8s rA0[8], rB0[4], rA1[8], rB1[4];

  const int o0 = tid * 8;          // short offset of chunk 0 (dest, linear)
  const int row0 = tid >> 2;       // 0..127
  const int cb0 = (((tid & 3) ^ ((tid >> 3) & 3))) * 8;   // swizzled src shorts

#define QK_STAGE_A(kt)                                                        \
  {                                                                           \
    const int kc_ = (kt) * 32;                                                \
    __builtin_amdgcn_global_load_lds(                                         \
        (const __attribute__((address_space(1))) void*)(xhi +                 \
            (size_t)(bt0 + row0) * E_ + kc_ + cb0),                           \
        (__attribute__((address_space(3))) void*)&LA[(kt) & 3][o0], 16, 0, 0);\
    __builtin_amdgcn_global_load_lds(                                         \
        (const __attribute__((address_space(1))) void*)(xhi +                 \
            (size_t)(bt0 + 128 + row0) * E_ + kc_ + cb0),                     \
        (__attribute__((address_space(3))) void*)&LA[(kt) & 3][o0 + 4096],    \
        16, 0, 0);                                                            \
  }
#define QK_STAGE_B(kt)                                                        \
  {                                                                           \
    const int kc_ = (kt) * 32;                                                \
    __builtin_amdgcn_global_load_lds(                                         \
        (const __attribute__((address_space(1))) void*)(wb +                  \
            (size_t)(j0 + row0) * E_ + kc_ + cb0),                            \
        (__attribute__((address_space(3))) void*)&LB[(kt) & 3][o0], 16, 0, 0);\
    __builtin_amdgcn_global_load_lds(                                         \
        (const __attribute__((address_space(1))) void*)(wb +                  \
            (size_t)(j0 + 128 + row0) * E_ + kc_ + cb0),                      \
        (__attribute__((address_space(3))) void*)&LB[(kt) & 3][o0 + 4096],    \
        16, 0, 0);                                                            \
  }
#define QK_READ_FULL(RA, RB, kt)                                              \
  {                                                                           \
    _Pragma("unroll") for (int i_ = 0; i_ < 8; ++i_) {                        \
      const int row_ = wr * 128 + i_ * 16 + col;                              \
      RA[i_] = *(const v8s*)&LA[(kt) & 3][row_ * 32 + qsz];                   \
    }                                                                         \
    _Pragma("unroll") for (int j_ = 0; j_ < 4; ++j_) {                        \
      const int row_ = wc * 64 + j_ * 16 + col;                               \
      RB[j_] = *(const v8s*)&LB[(kt) & 3][row_ * 32 + qsz];                   \
    }                                                                         \
  }
#define QK_MFMA_ALL(RA, RB)                                                   \
  __builtin_amdgcn_s_setprio(1);                                              \
  _Pragma("unroll") for (int i_ = 0; i_ < 8; ++i_)                            \
    _Pragma("unroll") for (int j_ = 0; j_ < 4; ++j_)                          \
      acc[i_][j_] = __builtin_amdgcn_mfma_f32_16x16x32_bf16(                  \
          RA[i_], RB[j_], acc[i_][j_], 0, 0, 0);                              \
  __builtin_amdgcn_s_setprio(0);

  QK_STAGE_A(0); QK_STAGE_B(0);
  QK_STAGE_A(1); QK_STAGE_B(1);
  QK_STAGE_A(2); QK_STAGE_B(2);
  QK_STAGE_A(3); QK_STAGE_B(3);
  asm volatile("s_waitcnt vmcnt(4)" ::: "memory");
  asm volatile("s_barrier" ::: "memory");
  QK_READ_FULL(rA0, rB0, 0);
  asm volatile("s_waitcnt lgkmcnt(0)" ::: "memory");

#pragma unroll 1
  for (int s = 0; s < 32; s += 2) {
    if (s < 31) QK_READ_FULL(rA1, rB1, s + 1);
    if (s + 4 < 32) { QK_STAGE_A(s + 4); QK_STAGE_B(s + 4); }
    QK_MFMA_ALL(rA0, rB0);
    if (s + 2 < 32) QK_READ_FULL(rA0, rB0, s + 2);
    if (s + 5 < 32) { QK_STAGE_A(s + 5); QK_STAGE_B(s + 5); }
    QK_MFMA_ALL(rA1, rB1);
    if (s <= 23) {
      asm volatile("s_waitcnt vmcnt(4)" ::: "memory");
    } else if (s <= 27) {
      asm volatile("s_waitcnt vmcnt(0)" ::: "memory");
    }
    asm volatile("s_barrier" ::: "memory");
  }

#undef QK_MFMA_ALL
#undef QK_READ_FULL
#undef QK_STAGE_B
#undef QK_STAGE_A

#pragma unroll
  for (int j = 0; j < 4; ++j) {
    const int n = j0 + wc * 64 + j * 16 + col;
    const int sec = n >> 10, nn = n & 1023, h = nn >> 6, dd = nn & 63;
    float* dst = (sec == 0) ? qb : kb;
    const float bv = bias[n];
#pragma unroll
    for (int i = 0; i < 8; ++i) {
      const int mbase = bt0 + wr * 128 + i * 16 + quad * 4;
#pragma unroll
      for (int r = 0; r < 4; ++r) {
        const int m = mbase + r;
        const int b = m >> 12, t = m & (T_ - 1);
        dst[((size_t)(b * H_ + h) * T_ + t) * D_ + dd] = acc[i][j][r] + bv;
      }
    }
  }
}

// ---------------------------------------------------------------------------
// V / Out GEMM (round-8 proven): qk ring structure at 128x256 tile,
// grid (64,4) = 256 blocks. BK=32, 4-slot ring, gload_lds width-16,
// chunk-XOR involution, counted vmcnt(3). mode 0: bf16 scatter to vbf
// layout; mode 1: fp32 linear. K = 1024 -> 32 steps. 8 waves (2Mx4N).
// ---------------------------------------------------------------------------
__global__ __launch_bounds__(512) void k_nko_mfma8(
    const unsigned short* __restrict__ Aa, const unsigned short* __restrict__ Bw,
    const float* __restrict__ bias, unsigned short* __restrict__ obf16,
    float* __restrict__ ofp32, int mode) {
  __shared__ __align__(16) unsigned short LA[4][4096];   // 128 rows x 32 K
  __shared__ __align__(16) unsigned short LB[4][8192];   // 256 rows x 32 K
  const int bt0 = blockIdx.x * 128, j0 = blockIdx.y * 256;
  const int tid = threadIdx.x;
  const int lane = tid & 63, w = tid >> 6;
  const int wr = w >> 2, wc = w & 3;          // 2 M-groups x 4 N-groups
  const int col = lane & 15, quad = lane >> 4;
  const int qsz = (quad ^ ((col >> 1) & 3)) * 8;
  f32x4 acc[4][4] = {};
  v8s rA0[4], rB0[4], rA1[4], rB1[4];

  const int o0 = tid * 8;          // dest short offset (linear)
  const int row0 = tid >> 2;       // 0..127
  const int cb0 = (((tid & 3) ^ ((tid >> 3) & 3))) * 8;   // swizzled src shorts

#define NK_STAGE(kt)                                                          \
  {                                                                           \
    const int kc_ = (kt) * 32;                                                \
    __builtin_amdgcn_global_load_lds(                                         \
        (const __attribute__((address_space(1))) void*)(Aa +                  \
            (size_t)(bt0 + row0) * E_ + kc_ + cb0),                           \
        (__attribute__((address_space(3))) void*)&LA[(kt) & 3][o0], 16, 0, 0);\
    __builtin_amdgcn_global_load_lds(                                         \
        (const __attribute__((address_space(1))) void*)(Bw +                  \
            (size_t)(j0 + row0) * E_ + kc_ + cb0),                            \
        (__attribute__((address_space(3))) void*)&LB[(kt) & 3][o0], 16, 0, 0);\
    __builtin_amdgcn_global_load_lds(                                         \
        (const __attribute__((address_space(1))) void*)(Bw +                  \
            (size_t)(j0 + 128 + row0) * E_ + kc_ + cb0),                      \
        (__attribute__((address_space(3))) void*)&LB[(kt) & 3][o0 + 4096],    \
        16, 0, 0);                                                            \
  }
#define NK_READ(RA, RB, kt)                                                   \
  {                                                                           \
    _Pragma("unroll") for (int i_ = 0; i_ < 4; ++i_) {                        \
      const int row_ = wr * 64 + i_ * 16 + col;                               \
      RA[i_] = *(const v8s*)&LA[(kt) & 3][row_ * 32 + qsz];                   \
    }                                                                         \
    _Pragma("unroll") for (int j_ = 0; j_ < 4; ++j_) {                        \
      const int row_ = wc * 64 + j_ * 16 + col;                               \
      RB[j_] = *(const v8s*)&LB[(kt) & 3][row_ * 32 + qsz];                   \
    }                                                                         \
  }
#define NK_MFMA(RA, RB)                                                       \
  __builtin_amdgcn_s_setprio(1);                                              \
  _Pragma("unroll") for (int i_ = 0; i_ < 4; ++i_)                            \
    _Pragma("unroll") for (int j_ = 0; j_ < 4; ++j_)                          \
      acc[i_][j_] = __builtin_amdgcn_mfma_f32_16x16x32_bf16(                  \
          RA[i_], RB[j_], acc[i_][j_], 0, 0, 0);                              \
  __builtin_amdgcn_s_setprio(0);

  NK_STAGE(0); NK_STAGE(1); NK_STAGE(2); NK_STAGE(3);
  asm volatile("s_waitcnt vmcnt(3)" ::: "memory");
  asm volatile("s_barrier" ::: "memory");
  NK_READ(rA0, rB0, 0);
  asm volatile("s_waitcnt lgkmcnt(0)" ::: "memory");

#pragma unroll 1
  for (int s = 0; s < 28; s += 2) {
    NK_READ(rA1, rB1, s + 1);
    NK_STAGE(s + 4);
    NK_MFMA(rA0, rB0);
    NK_READ(rA0, rB0, s + 2);
    NK_STAGE(s + 5);
    NK_MFMA(rA1, rB1);
    asm volatile("s_waitcnt vmcnt(3)" ::: "memory");
    asm volatile("s_barrier" ::: "memory");
  }
  // s = 28: no stages remain; drain last tile (31)
  NK_READ(rA1, rB1, 29);
  NK_MFMA(rA0, rB0);
  NK_READ(rA0, rB0, 30);
  NK_MFMA(rA1, rB1);
  asm volatile("s_waitcnt vmcnt(0)" ::: "memory");
  asm volatile("s_barrier" ::: "memory");
  // s = 30
  NK_READ(rA1, rB1, 31);
  NK_MFMA(rA0, rB0);
  NK_MFMA(rA1, rB1);

#undef NK_MFMA
#undef NK_READ
#undef NK_STAGE

#pragma unroll
  for (int j = 0; j < 4; ++j) {
    const int n = j0 + wc * 64 + j * 16 + col;   // 0..1023
    const float bv = bias[n];
    const int h = n >> 6, dd = n & 63;
#pragma unroll
    for (int i = 0; i < 4; ++i) {
      const int mbase = bt0 + wr * 64 + i * 16 + quad * 4;
#pragma unroll
      for (int r = 0; r < 4; ++r) {
        const int m = mbase + r;
        const float val = acc[i][j][r] + bv;
        if (mode == 0) {
          const int b = m >> 12, t = m & (T_ - 1);
          obf16[((size_t)(b * H_ + h) * T_ + t) * D_ + dd] = f2bf(val);
        } else {
          ofp32[(size_t)m * E_ + n] = val;
        }
      }
    }
  }
}

// ---------------------------------------------------------------------------
// Features via MFMA (unchanged)
// ---------------------------------------------------------------------------
__global__ __launch_bounds__(256) void k_feat_mfma(
    const float* __restrict__ xin, const float* __restrict__ poly_w,
    const float* __restrict__ omega, const float* __restrict__ qnod,
    const float* __restrict__ qwt, unsigned short* __restrict__ pqb,
    unsigned short* __restrict__ fqb) {
  __shared__ __align__(16) unsigned short XH[128 * 72];
  __shared__ __align__(16) unsigned short XL[128 * 72];
  __shared__ __align__(16) unsigned short Bs[80 * 72];
  const int bh = blockIdx.x >> 5;
  const int t0 = (blockIdx.x & 31) * 128;
  const int h = bh & (H_ - 1);
  const int tid = threadIdx.x, lane = tid & 63, w = tid >> 6;
  const int col = lane & 15, quad = lane >> 4;
  const size_t rowB = (size_t)bh * T_ + t0;

  const float s0 = qnod[0];
  const float sq2 = sqrtf(fmaxf(2.f * s0, 0.f));
  const float scale = sqrtf(fmaxf(qwt[0], 0.f)) * 0.3535533905932738f;

  for (int rr = 0; rr < 32; ++rr) {
    const int t = w * 32 + rr;
    const float xv = xin[(rowB + t) * D_ + lane];
    float ss = xv * xv;
#pragma unroll
    for (int off = 32; off > 0; off >>= 1) ss += __shfl_xor(ss, off);
    const float rn = 1.0f / fmaxf(sqrtf(ss), 1e-12f);
    const float xn = xv * rn;
    const unsigned short hi = f2bf(xn);
    XH[t * 72 + lane] = hi;
    XL[t * 72 + lane] = f2bf(xn - bf2f(hi));
  }
  {
    const int base = tid * 16;
#pragma unroll
    for (int j4 = 0; j4 < 4; ++j4) {
      const int idx = base + j4 * 4;
      const int d = idx >> 6, p = idx & 63;
      const float4 v = *(const float4*)(poly_w + (size_t)h * 4096 + idx);
      Bs[(p + 0) * 72 + d] = f2bf(v.x);
      Bs[(p + 1) * 72 + d] = f2bf(v.y);
      Bs[(p + 2) * 72 + d] = f2bf(v.z);
      Bs[(p + 3) * 72 + d] = f2bf(v.w);
    }
    if (tid < 128) {
      const int idx = tid * 4;
      const int d = idx >> 3, m0 = idx & 7;
      const float4 v = *(const float4*)(omega + (size_t)h * 512 + idx);
      Bs[(64 + m0 + 0) * 72 + d] = f2bf(v.x);
      Bs[(64 + m0 + 1) * 72 + d] = f2bf(v.y);
      Bs[(64 + m0 + 2) * 72 + d] = f2bf(v.z);
      Bs[(64 + m0 + 3) * 72 + d] = f2bf(v.w);
    }
  }
  __syncthreads();
  f32x4 acc[2][5] = {};
#pragma unroll
  for (int kk = 0; kk < 2; ++kk) {
    v8s ah[2], al[2];
#pragma unroll
    for (int i = 0; i < 2; ++i) {
      const int mo = ((2 * w + i) * 16 + col) * 72 + kk * 32 + quad * 8;
      ah[i] = *(const v8s*)&XH[mo];
      al[i] = *(const v8s*)&XL[mo];
    }
#pragma unroll
    for (int nt = 0; nt < 5; ++nt) {
      const v8s bb = *(const v8s*)&Bs[(nt * 16 + col) * 72 + kk * 32 + quad * 8];
#pragma unroll
      for (int i = 0; i < 2; ++i) {
        acc[i][nt] = __builtin_amdgcn_mfma_f32_16x16x32_bf16(ah[i], bb, acc[i][nt], 0, 0, 0);
        acc[i][nt] = __builtin_amdgcn_mfma_f32_16x16x32_bf16(al[i], bb, acc[i][nt], 0, 0, 0);
      }
    }
  }
#pragma unroll
  for (int i = 0; i < 2; ++i) {
#pragma unroll
    for (int r = 0; r < 4; ++r) {
      const int t = (2 * w + i) * 16 + quad * 4 + r;
#pragma unroll
      for (int nt = 0; nt < 4; ++nt) {
        const float c = acc[i][nt][r];
        pqb[(rowB + t) * P_ + nt * 16 + col] = f2bf(c * c * 0.125f);
      }
      if (col < 8) {
        const float c = acc[i][4][r];
        const float z = fminf(fmaxf(c * sq2 - s0, -20.f), 20.f);
        fqb[(rowB + t) * M_ + col] = f2bf(expf(z) * scale);
      }
    }
  }
}

// ---------------------------------------------------------------------------
// Phase A via MFMA (unchanged)
// ---------------------------------------------------------------------------
__global__ __launch_bounds__(512) void k_phaseA(
    const unsigned short* __restrict__ pkb, const unsigned short* __restrict__ fkb,
    const unsigned short* __restrict__ vbf, unsigned short* __restrict__ kvch,
    float* __restrict__ ksum) {
  __shared__ __align__(16) unsigned short VT[64 * 72];
  __shared__ __align__(16) unsigned short pkT[64 * 72];
  __shared__ __align__(16) unsigned short fkT[8 * 72];
  const int bh = blockIdx.x & (BH_ - 1);
  const int c = blockIdx.x >> 5;
  const size_t rowC = (size_t)bh * T_ + (size_t)c * CH_;
  const int tid = threadIdx.x, lane = tid & 63, w = tid >> 6;
  const int col = lane & 15, quad = lane >> 4;
  const int nb = w * 64;
  f32x4 acc[4][4] = {};
  float ks[4] = {0.f, 0.f, 0.f, 0.f};

  for (int st = 0; st < 4; ++st) {
    const size_t t0 = rowC + st * 64;
    __syncthreads();
#pragma unroll
    for (int ps = 0; ps < 2; ++ps) {
      const int idx = ps * 512 + tid;
      const int t = idx >> 4, dg = (idx & 15) * 4;
      const ushort4 v = *(const ushort4*)(vbf + (t0 + t) * D_ + dg);
      VT[(dg + 0) * 72 + t] = v.x;
      VT[(dg + 1) * 72 + t] = v.y;
      VT[(dg + 2) * 72 + t] = v.z;
      VT[(dg + 3) * 72 + t] = v.w;
    }
    {
      const int t = tid >> 3, pg = (tid & 7) * 8;
      const v8s pv = *(const v8s*)(pkb + (t0 + t) * P_ + pg);
#pragma unroll
      for (int j = 0; j < 8; ++j) pkT[(pg + j) * 72 + t] = (unsigned short)pv[j];
    }
    if (tid < 64) {
      const v8s fv = *(const v8s*)(fkb + (t0 + tid) * M_);
#pragma unroll
      for (int j = 0; j < 8; ++j) fkT[j * 72 + tid] = (unsigned short)fv[j];
    }
    __syncthreads();
#pragma unroll
    for (int kk = 0; kk < 2; ++kk) {
      v8s a[4];
#pragma unroll
      for (int mt = 0; mt < 4; ++mt)
        a[mt] = *(const v8s*)&VT[(mt * 16 + col) * 72 + kk * 32 + quad * 8];
#pragma unroll
      for (int nt = 0; nt < 4; ++nt) {
        const int pm = nb + nt * 16 + col;
        const int p = pm >> 3, m8 = pm & 7;
        const v8s pkv = *(const v8s*)&pkT[p * 72 + kk * 32 + quad * 8];
        const v8s fkv = *(const v8s*)&fkT[m8 * 72 + kk * 32 + quad * 8];
        v8s bfrag;
        float kss = 0.f;
#pragma unroll
        for (int j = 0; j < 8; ++j) {
          const float v = bf2f((unsigned short)pkv[j]) * bf2f((unsigned short)fkv[j]);
          kss += v;
          bfrag[j] = (short)f2bf(v);
        }
        ks[nt] += kss;
#pragma unroll
        for (int mt = 0; mt < 4; ++mt)
          acc[mt][nt] = __builtin_amdgcn_mfma_f32_16x16x32_bf16(a[mt], bfrag, acc[mt][nt], 0, 0, 0);
      }
    }
  }
  const size_t base = (size_t)(c * BH_ + bh) * D_ * F_;
#pragma unroll
  for (int nt = 0; nt < 4; ++nt) {
    const int pm = nb + nt * 16 + col;
#pragma unroll
    for (int mt = 0; mt < 4; ++mt) {
#pragma unroll
      for (int r = 0; r < 4; ++r) {
        const int d = mt * 16 + quad * 4 + r;
        kvch[base + (size_t)d * F_ + pm] = f2bf(acc[mt][nt][r]);
      }
    }
    float kv_ = ks[nt];
    kv_ += __shfl_xor(kv_, 16);
    kv_ += __shfl_xor(kv_, 32);
    if (quad == 0) ksum[(size_t)(c * BH_ + bh) * F_ + pm] = kv_;
  }
}

// ---------------------------------------------------------------------------
__global__ __launch_bounds__(256) void k_scan_kv(unsigned short* __restrict__ kvch) {
  const size_t s = (size_t)blockIdx.x * 256 + threadIdx.x;
  const size_t stride = (size_t)BH_ * D_ * F_;
  unsigned short v[NC_];
#pragma unroll
  for (int c = 0; c < NC_; ++c) v[c] = kvch[(size_t)c * stride + s];
  float run = 0.f;
#pragma unroll
  for (int c = 0; c < NC_; ++c) {
    const float t = bf2f(v[c]);
    kvch[(size_t)c * stride + s] = f2bf(run);
    run += t;
  }
}

__global__ __launch_bounds__(256) void k_scan_ks(float* __restrict__ ksum) {
  const int s = blockIdx.x * 256 + threadIdx.x;
  const int stride = BH_ * F_;
  float v[NC_];
#pragma unroll
  for (int c = 0; c < NC_; ++c) v[c] = ksum[c * stride + s];
  float run = 0.f;
#pragma unroll
  for (int c = 0; c < NC_; ++c) {
    const float t = v[c];
    ksum[c * stride + s] = run;
    run += t;
  }
}

// ---------------------------------------------------------------------------
// Fused scores+intra (round-11 version: pk/fk LDS staging + 3rd-MFMA fusion)
// ---------------------------------------------------------------------------
__global__ __launch_bounds__(256) void k_sintra(
    const unsigned short* __restrict__ pqb, const unsigned short* __restrict__ fqb,
    const unsigned short* __restrict__ pkb, const unsigned short* __restrict__ fkb,
    const unsigned short* __restrict__ vbf, float* __restrict__ obuf,
    float* __restrict__ nrmbuf) {
  __shared__ __align__(16) unsigned short S_lds[128 * 136];
  __shared__ __align__(16) unsigned short VT[64 * 136];
  __shared__ __align__(16) unsigned short pkT[128 * 72];
  __shared__ __align__(16) unsigned short fkT[128 * 8];
  const int bh = blockIdx.x & (BH_ - 1);
  const int tq = blockIdx.x >> 5;
  const int c = tq >> 1, h2 = tq & 1;
  const size_t rowT = (size_t)bh * T_ + (size_t)tq * 128;
  const size_t rowC = (size_t)bh * T_ + (size_t)c * CH_;
  const int tid = threadIdx.x, lane = tid & 63, w = tid >> 6;
  const int col = lane & 15, quad = lane >> 4;

  const v8s vzero = {};
  v8s bq[2][2], bqf[2];
#pragma unroll
  for (int i = 0; i < 2; ++i) {
    const size_t qrow = rowT + (2 * w + i) * 16 + col;
    bq[i][0] = *(const v8s*)(pqb + qrow * P_ + quad * 8);
    bq[i][1] = *(const v8s*)(pqb + qrow * P_ + 32 + quad * 8);
    const v8s fv = *(const v8s*)(fqb + qrow * M_);
    bqf[i] = (quad == 0) ? fv : vzero;
  }
  f32x4 acc[2][4] = {};
  float rs[2] = {0.f, 0.f};

  const int vd = tid & 63, vg = tid >> 6;

  for (int sl = 0; sl <= h2; ++sl) {
    const size_t rowS = rowC + (size_t)sl * 128;
    __syncthreads();
#pragma unroll
    for (int c4 = 0; c4 < 4; ++c4) {
      const int g = c4 * 256 + tid;
      const int row = g >> 3, ch = g & 7;
      *(v8s*)&pkT[row * 72 + ch * 8] =
          *(const v8s*)(pkb + (rowS + row) * P_ + ch * 8);
    }
    if (tid < 128)
      *(v8s*)&fkT[tid * 8] = *(const v8s*)(fkb + (rowS + tid) * M_);
#pragma unroll
    for (int j8 = 0; j8 < 4; ++j8) {
      const int s0 = vg * 32 + j8 * 8;
      v8s pv;
#pragma unroll
      for (int k = 0; k < 8; ++k)
        pv[k] = (short)vbf[(rowS + s0 + k) * D_ + vd];
      *(v8s*)&VT[vd * 136 + s0] = pv;
    }
    __syncthreads();
    for (int si = 0; si < 8; ++si) {
      const int srow = si * 16 + col;
      const v8s a0 = *(const v8s*)&pkT[srow * 72 + quad * 8];
      const v8s a1 = *(const v8s*)&pkT[srow * 72 + 32 + quad * 8];
      const v8s af = (quad == 0) ? *(const v8s*)&fkT[srow * 8] : vzero;
#pragma unroll
      for (int i = 0; i < 2; ++i) {
        const int tt = 2 * w + i;
        const int t_rel = h2 * 128 + tt * 16 + col;
        f32x4 sp = {};
        sp = __builtin_amdgcn_mfma_f32_16x16x32_bf16(a0, bq[i][0], sp, 0, 0, 0);
        sp = __builtin_amdgcn_mfma_f32_16x16x32_bf16(a1, bq[i][1], sp, 0, 0, 0);
        f32x4 spf = {};
        spf = __builtin_amdgcn_mfma_f32_16x16x32_bf16(af, bqf[i], spf, 0, 0, 0);
        ushort4 pk4;
        float partial = 0.f;
#pragma unroll
        for (int r = 0; r < 4; ++r) {
          const int s_in = si * 16 + quad * 4 + r;
          float val = sp[r] * spf[r];
          const int s_rel = sl * 128 + s_in;
          val = (s_rel <= t_rel) ? val : 0.f;
          partial += val;
          ((unsigned short*)&pk4)[r] = f2bf(val);
        }
        rs[i] += partial;
        *(ushort4*)&S_lds[(tt * 16 + col) * 136 + si * 16 + quad * 4] = pk4;
      }
    }
    __syncthreads();
#pragma unroll
    for (int i = 0; i < 2; ++i) {
      const int tt = 2 * w + i;
#pragma unroll
      for (int kk = 0; kk < 4; ++kk) {
        const v8s sa = *(const v8s*)&S_lds[(tt * 16 + col) * 136 + kk * 32 + quad * 8];
#pragma unroll
        for (int dt = 0; dt < 4; ++dt) {
          const v8s vb8 = *(const v8s*)&VT[(dt * 16 + col) * 136 + kk * 32 + quad * 8];
          acc[i][dt] = __builtin_amdgcn_mfma_f32_16x16x32_bf16(sa, vb8, acc[i][dt], 0, 0, 0);
        }
      }
    }
  }
#pragma unroll
  for (int i = 0; i < 2; ++i) {
#pragma unroll
    for (int dt = 0; dt < 4; ++dt) {
#pragma unroll
      for (int r = 0; r < 4; ++r) {
        const int t = (2 * w + i) * 16 + quad * 4 + r;
        obuf[(rowT + t) * D_ + dt * 16 + col] = acc[i][dt][r];
      }
    }
    rs[i] += __shfl_xor(rs[i], 16);
    rs[i] += __shfl_xor(rs[i], 32);
  }
  if (lane < 16) {
    const size_t nbase = (size_t)(c * BH_ + bh) * CH_ + h2 * 128;
    nrmbuf[nbase + (2 * w + 0) * 16 + lane] = rs[0];
    nrmbuf[nbase + (2 * w + 1) * 16 + lane] = rs[1];
  }
}

// ---------------------------------------------------------------------------
// Hist via MFMA (unchanged)
// ---------------------------------------------------------------------------
__global__ __launch_bounds__(256) void k_hist(
    const unsigned short* __restrict__ pqb, const unsigned short* __restrict__ fqb,
    const unsigned short* __restrict__ kvch, const float* __restrict__ ksum,
    const float* __restrict__ nrmbuf, const float* __restrict__ obuf,
    unsigned short* __restrict__ obf) {
  __shared__ __align__(16) unsigned short QF_lds[128 * 72];
  __shared__ __align__(16) unsigned short KV_lds[64 * 72];
  __shared__ float kp_lds[F_];
  __shared__ float nhs[128];
  const int half = blockIdx.x & 1;
  const int bh = (blockIdx.x >> 1) & (BH_ - 1);
  const int c = blockIdx.x >> 6;
  const int b = bh >> 4, h = bh & (H_ - 1);
  const int tid = threadIdx.x, lane = tid & 63, w = tid >> 6;
  const int col = lane & 15, quad = lane >> 4;
  const size_t rowQ = (size_t)bh * T_ + (size_t)c * CH_ + half * 128;
  const size_t kvbase = (size_t)(c * BH_ + bh) * D_ * F_;

  const int tr = tid >> 1, side = tid & 1;
  float fqr[8];
  {
    const v8s fv = *(const v8s*)(fqb + (rowQ + tr) * M_);
#pragma unroll
    for (int j = 0; j < 8; ++j) fqr[j] = bf2f((unsigned short)fv[j]);
    if (tid < 128)
      *(float4*)(&kp_lds[tid * 4]) =
          *(const float4*)(ksum + (size_t)(c * BH_ + bh) * F_ + tid * 4);
  }
  f32x4 acc[2][4] = {};
  float nh_part = 0.f;
  const int gr = tid & 7, d0 = tid >> 3;

  for (int pmt = 0; pmt < 8; ++pmt) {
    __syncthreads();
#pragma unroll
    for (int pp = 0; pp < 2; ++pp) {
      const int d = d0 + pp * 32;
      *(v8s*)&KV_lds[d * 72 + gr * 8] =
          *(const v8s*)(kvch + kvbase + (size_t)d * F_ + pmt * 64 + gr * 8);
    }
    {
      const v8s pq8 = *(const v8s*)(pqb + (rowQ + tr) * P_ + pmt * 8);
#pragma unroll
      for (int pp = 0; pp < 4; ++pp) {
        const int pl = side * 4 + pp;
        const float pqf = bf2f((unsigned short)pq8[pl]);
        const int kb_ = (pmt * 8 + pl) * 8;
        v8s o;
#pragma unroll
        for (int j = 0; j < 8; ++j) {
          const float v = pqf * fqr[j];
          nh_part += v * kp_lds[kb_ + j];
          o[j] = (short)f2bf(v);
        }
        *(v8s*)&QF_lds[tr * 72 + pl * 8] = o;
      }
    }
    __syncthreads();
#pragma unroll
    for (int kk = 0; kk < 2; ++kk) {
      v8s a[2], bb[4];
#pragma unroll
      for (int i = 0; i < 2; ++i)
        a[i] = *(const v8s*)&QF_lds[((2 * w + i) * 16 + col) * 72 + kk * 32 + quad * 8];
#pragma unroll
      for (int j = 0; j < 4; ++j)
        bb[j] = *(const v8s*)&KV_lds[(j * 16 + col) * 72 + kk * 32 + quad * 8];
#pragma unroll
      for (int i = 0; i < 2; ++i)
#pragma unroll
        for (int j = 0; j < 4; ++j)
          acc[i][j] = __builtin_amdgcn_mfma_f32_16x16x32_bf16(a[i], bb[j], acc[i][j], 0, 0, 0);
    }
  }
  {
    const float nh = nh_part + __shfl_xor(nh_part, 1);
    if (!(tid & 1)) nhs[tr] = nh;
  }
  __syncthreads();
  const size_t nbase = (size_t)(c * BH_ + bh) * CH_ + half * 128;
#pragma unroll
  for (int i = 0; i < 2; ++i) {
#pragma unroll
    for (int r = 0; r < 4; ++r) {
      const int t = (2 * w + i) * 16 + quad * 4 + r;
      const float nrm = nhs[t] + nrmbuf[nbase + t] + 1e-6f;
      const float rcp = 1.0f / nrm;
#pragma unroll
      for (int j = 0; j < 4; ++j) {
        const int d = j * 16 + col;
        const float val = (obuf[(rowQ + t) * D_ + d] + acc[i][j][r]) * rcp;
        obf[(size_t)(b * T_ + c * CH_ + half * 128 + t) * E_ + h * 64 + d] = f2bf(val);
      }
    }
  }
}

// ---------------------------------------------------------------------------
extern "C" void kernel_launch(void* const* d_in, const int* in_sizes, int n_in,
                              void* d_out, int out_size, void* d_ws, size_t ws_size,
                              hipStream_t stream) {
  (void)in_sizes; (void)n_in; (void)out_size; (void)ws_size;
  const float* x      = (const float*)d_in[0];
  const float* qkv_w  = (const float*)d_in[1];
  const float* qkv_b  = (const float*)d_in[2];
  const float* out_w  = (const float*)d_in[3];
  const float* out_b  = (const float*)d_in[4];
  const float* omega  = (const float*)d_in[5];
  const float* poly_w = (const float*)d_in[6];
  const float* qnod   = (const float*)d_in[7];
  const float* qwt    = (const float*)d_in[8];
  float* ws = (float*)d_ws;
  float* qb   = ws + OFF_Q;
  float* kb   = ws + OFF_K;
  unsigned short* vbf = (unsigned short*)(ws + OFF_V);
  unsigned short* fqb = (unsigned short*)(ws + OFF_FQ);
  unsigned short* fkb = (unsigned short*)(ws + OFF_FK);
  float* ksb  = ws + OFF_KS;
  float* nrmb = ws + OFF_NRM;
  float* ob   = ws + OFF_O;
  unsigned short* kvb = (unsigned short*)(ws + OFF_KV);
  unsigned short* pqb = kvb + 16777216;
  unsigned short* pkb = pqb + SZ_BHTD;
  unsigned short* xhi  = kvb;
  unsigned short* xlo  = kvb + SZ_BHTD;
  unsigned short* wqkv = kvb + 2 * SZ_BHTD;
  unsigned short* obf   = (unsigned short*)kb;
  unsigned short* woutb = (unsigned short*)(ws + OFF_V);  // over dead v (post-sintra)
  float* outp = (float*)d_out;

  hipLaunchKernelGGL(k_split_x, dim3(8192), dim3(256), 0, stream, x, xhi, xlo);
  hipLaunchKernelGGL(k_cast_w, dim3(3072), dim3(256), 0, stream, qkv_w, wqkv);
  hipLaunchKernelGGL(k_qk_mfma8, dim3(BT_ / 256, 8), dim3(512), 0, stream,
                     xhi, xlo, wqkv, qkv_b, qb, kb);
  hipLaunchKernelGGL(k_nko_mfma8, dim3(BT_ / 128, 4), dim3(512), 0, stream,
                     xhi, wqkv + (size_t)2048 * E_, qkv_b + 2048, vbf,
                     (float*)nullptr, 0);
  hipLaunchKernelGGL(k_feat_mfma, dim3(1024), dim3(256), 0, stream,
                     qb, poly_w, omega, qnod, qwt, pqb, fqb);
  hipLaunchKernelGGL(k_feat_mfma, dim3(1024), dim3(256), 0, stream,
                     kb, poly_w, omega, qnod, qwt, pkb, fkb);
  hipLaunchKernelGGL(k_phaseA, dim3(NC_ * BH_), dim3(512), 0, stream,
                     pkb, fkb, vbf, kvb, ksb);
  hipLaunchKernelGGL(k_scan_kv, dim3(4096), dim3(256), 0, stream, kvb);
  hipLaunchKernelGGL(k_scan_ks, dim3(64), dim3(256), 0, stream, ksb);
  hipLaunchKernelGGL(k_sintra, dim3(BH_ * 32), dim3(256), 0, stream,
                     pqb, fqb, pkb, fkb, vbf, ob, nrmb);
  hipLaunchKernelGGL(k_cast_w, dim3(1024), dim3(256), 0, stream, out_w, woutb);
  hipLaunchKernelGGL(k_hist, dim3(NC_ * BH_ * 2), dim3(256), 0, stream,
                     pqb, fqb, kvb, ksb, nrmb, ob, obf);
  hipLaunchKernelGGL(k_nko_mfma8, dim3(BT_ / 128, 4), dim3(512), 0, stream,
                     obf, woutb, out_b, (unsigned short*)nullptr, outp, 1);
}

// Round 10
// 338.305 us; speedup vs baseline: 1.2779x; 1.1749x over previous
//
#include <hip/hip_runtime.h>
#include <math.h>

#define B_ 2
#define T_ 4096
#define E_ 1024
#define H_ 16
#define D_ 64
#define P_ 64
#define M_ 8
#define CH_ 256
#define NC_ 16
#define F_ 512
#define BH_ 32
#define BT_ 8192

// ---- workspace layout ----
static constexpr size_t SZ_BHTD = (size_t)B_ * H_ * T_ * D_;     // 8,388,608
static constexpr size_t SZ_PRF  = (size_t)B_ * H_ * T_ * M_;     // 1,048,576
static constexpr size_t SZ_KS   = (size_t)NC_ * BH_ * F_;        // 262,144
static constexpr size_t SZ_NRM  = (size_t)NC_ * BH_ * CH_;       // 131,072
static constexpr size_t SZ_KV_E = 33554432;                      // bf16 region

static constexpr size_t OFF_Q   = 0;
static constexpr size_t OFF_K   = OFF_Q + SZ_BHTD;
static constexpr size_t OFF_V   = OFF_K + SZ_BHTD;    // v bf16 (half used); woutb overlay later
static constexpr size_t OFF_FQ  = OFF_V + SZ_BHTD;
static constexpr size_t OFF_FK  = OFF_FQ + SZ_PRF;
static constexpr size_t OFF_KS  = OFF_FK + SZ_PRF;
static constexpr size_t OFF_NRM = OFF_KS + SZ_KS;
static constexpr size_t OFF_O   = OFF_NRM + SZ_NRM;
static constexpr size_t OFF_KV  = OFF_O + SZ_BHTD;
// total = OFF_KV*4 + SZ_KV_E*2 = 211,288,064 B (~201.5 MiB)

__device__ __forceinline__ float bf2f(unsigned short u) {
  union { unsigned u32; float f; } x; x.u32 = ((unsigned)u) << 16; return x.f;
}
__device__ __forceinline__ unsigned short f2bf(float f) {
  union { float f; unsigned u; } x; x.f = f;
  unsigned r = x.u + 0x7fffu + ((x.u >> 16) & 1u);
  return (unsigned short)(r >> 16);
}

typedef short v8s __attribute__((ext_vector_type(8)));
typedef float f32x4 __attribute__((ext_vector_type(4)));
#define LDSA 72   // GEMM LDS stride (bf16) for the remaining 128-tile GEMMs

// ---------------------------------------------------------------------------
// hi-only x (lo-pass dropped from qk — verified round 9; xlo dead)
__global__ __launch_bounds__(256) void k_split_x(
    const float* __restrict__ x, unsigned short* __restrict__ hi,
    unsigned short* __restrict__ lo) {
  (void)lo;
  const size_t i4 = ((size_t)blockIdx.x * 256 + threadIdx.x) * 4;
  const float4 v = *(const float4*)(x + i4);
  ushort4 h;
  h.x = f2bf(v.x); h.y = f2bf(v.y); h.z = f2bf(v.z); h.w = f2bf(v.w);
  *(ushort4*)(hi + i4) = h;
}

__global__ __launch_bounds__(256) void k_cast_w(
    const float* __restrict__ w, unsigned short* __restrict__ wb) {
  const size_t i4 = ((size_t)blockIdx.x * 256 + threadIdx.x) * 4;
  const float4 v = *(const float4*)(w + i4);
  ushort4 h;
  h.x = f2bf(v.x); h.y = f2bf(v.y); h.z = f2bf(v.z); h.w = f2bf(v.w);
  *(ushort4*)(wb + i4) = h;
}

// ---------------------------------------------------------------------------
// Q/K GEMM (round-9 verified): hi-only A, K=1024 -> 32 steps. 256x256, BK=32,
// 16x16x32 MFMA, 4-slot ring, register pipeline, 2-bit chunk-XOR involution
// (0 bank conflicts), barrier per 2 K-steps, counted vmcnt(4). grid (32,8).
// ---------------------------------------------------------------------------
__global__ __launch_bounds__(512) void k_qk_mfma8(
    const unsigned short* __restrict__ xhi, const unsigned short* __restrict__ xlo,
    const unsigned short* __restrict__ wb, const float* __restrict__ bias,
    float* __restrict__ qb, float* __restrict__ kb) {
  (void)xlo;
  __shared__ __align__(16) unsigned short LA[4][8192];   // 4 slots x 256 rows x 32 K
  __shared__ __align__(16) unsigned short LB[4][8192];   // 64 KiB + 64 KiB
  const int bt0 = blockIdx.x * 256, j0 = blockIdx.y * 256;
  const int tid = threadIdx.x;
  const int lane = tid & 63, w = tid >> 6;
  const int wr = w >> 2, wc = w & 3;          // 2 M-groups x 4 N-groups
  const int col = lane & 15, quad = lane >> 4;
  const int qsz = (quad ^ ((col >> 1) & 3)) * 8;
  f32x4 acc[8][4] = {};
  v8s rA0[8], rB0[4], rA1[8], rB1[4];

  const int o0 = tid * 8;          // short offset of chunk 0 (dest, linear)
  const int row0 = tid >> 2;       // 0..127
  const int cb0 = (((tid & 3) ^ ((tid >> 3) & 3))) * 8;   // swizzled src shorts

#define QK_STAGE_A(kt)                                                        \
  {                                                                           \
    const int kc_ = (kt) * 32;                                                \
    __builtin_amdgcn_global_load_lds(                                         \
        (const __attribute__((address_space(1))) void*)(xhi +                 \
            (size_t)(bt0 + row0) * E_ + kc_ + cb0),                           \
        (__attribute__((address_space(3))) void*)&LA[(kt) & 3][o0], 16, 0, 0);\
    __builtin_amdgcn_global_load_lds(                                         \
        (const __attribute__((address_space(1))) void*)(xhi +                 \
            (size_t)(bt0 + 128 + row0) * E_ + kc_ + cb0),                     \
        (__attribute__((address_space(3))) void*)&LA[(kt) & 3][o0 + 4096],    \
        16, 0, 0);                                                            \
  }
#define QK_STAGE_B(kt)                                                        \
  {                                                                           \
    const int kc_ = (kt) * 32;                                                \
    __builtin_amdgcn_global_load_lds(                                         \
        (const __attribute__((address_space(1))) void*)(wb +                  \
            (size_t)(j0 + row0) * E_ + kc_ + cb0),                            \
        (__attribute__((address_space(3))) void*)&LB[(kt) & 3][o0], 16, 0, 0);\
    __builtin_amdgcn_global_load_lds(                                         \
        (const __attribute__((address_space(1))) void*)(wb +                  \
            (size_t)(j0 + 128 + row0) * E_ + kc_ + cb0),                      \
        (__attribute__((address_space(3))) void*)&LB[(kt) & 3][o0 + 4096],    \
        16, 0, 0);                                                            \
  }
#define QK_READ_FULL(RA, RB, kt)                                              \
  {                                                                           \
    _Pragma("unroll") for (int i_ = 0; i_ < 8; ++i_) {                        \
      const int row_ = wr * 128 + i_ * 16 + col;                              \
      RA[i_] = *(const v8s*)&LA[(kt) & 3][row_ * 32 + qsz];                   \
    }                                                                         \
    _Pragma("unroll") for (int j_ = 0; j_ < 4; ++j_) {                        \
      const int row_ = wc * 64 + j_ * 16 + col;                               \
      RB[j_] = *(const v8s*)&LB[(kt) & 3][row_ * 32 + qsz];                   \
    }                                                                         \
  }
#define QK_MFMA_ALL(RA, RB)                                                   \
  __builtin_amdgcn_s_setprio(1);                                              \
  _Pragma("unroll") for (int i_ = 0; i_ < 8; ++i_)                            \
    _Pragma("unroll") for (int j_ = 0; j_ < 4; ++j_)                          \
      acc[i_][j_] = __builtin_amdgcn_mfma_f32_16x16x32_bf16(                  \
          RA[i_], RB[j_], acc[i_][j_], 0, 0, 0);                              \
  __builtin_amdgcn_s_setprio(0);

  QK_STAGE_A(0); QK_STAGE_B(0);
  QK_STAGE_A(1); QK_STAGE_B(1);
  QK_STAGE_A(2); QK_STAGE_B(2);
  QK_STAGE_A(3); QK_STAGE_B(3);
  asm volatile("s_waitcnt vmcnt(4)" ::: "memory");
  asm volatile("s_barrier" ::: "memory");
  QK_READ_FULL(rA0, rB0, 0);
  asm volatile("s_waitcnt lgkmcnt(0)" ::: "memory");

#pragma unroll 1
  for (int s = 0; s < 32; s += 2) {
    if (s < 31) QK_READ_FULL(rA1, rB1, s + 1);
    if (s + 4 < 32) { QK_STAGE_A(s + 4); QK_STAGE_B(s + 4); }
    QK_MFMA_ALL(rA0, rB0);
    if (s + 2 < 32) QK_READ_FULL(rA0, rB0, s + 2);
    if (s + 5 < 32) { QK_STAGE_A(s + 5); QK_STAGE_B(s + 5); }
    QK_MFMA_ALL(rA1, rB1);
    if (s <= 23) {
      asm volatile("s_waitcnt vmcnt(4)" ::: "memory");
    } else if (s <= 27) {
      asm volatile("s_waitcnt vmcnt(0)" ::: "memory");
    }
    asm volatile("s_barrier" ::: "memory");
  }

#undef QK_MFMA_ALL
#undef QK_READ_FULL
#undef QK_STAGE_B
#undef QK_STAGE_A

#pragma unroll
  for (int j = 0; j < 4; ++j) {
    const int n = j0 + wc * 64 + j * 16 + col;
    const int sec = n >> 10, nn = n & 1023, h = nn >> 6, dd = nn & 63;
    float* dst = (sec == 0) ? qb : kb;
    const float bv = bias[n];
#pragma unroll
    for (int i = 0; i < 8; ++i) {
      const int mbase = bt0 + wr * 128 + i * 16 + quad * 4;
#pragma unroll
      for (int r = 0; r < 4; ++r) {
        const int m = mbase + r;
        const int b = m >> 12, t = m & (T_ - 1);
        dst[((size_t)(b * H_ + h) * T_ + t) * D_ + dd] = acc[i][j][r] + bv;
      }
    }
  }
}

// ---------------------------------------------------------------------------
// V / Out GEMM (round-8 proven): qk ring structure at 128x256 tile,
// grid (64,4) = 256 blocks. BK=32, 4-slot ring, gload_lds width-16,
// chunk-XOR involution, counted vmcnt(3). mode 0: bf16 scatter to vbf
// layout; mode 1: fp32 linear. K = 1024 -> 32 steps. 8 waves (2Mx4N).
// ---------------------------------------------------------------------------
__global__ __launch_bounds__(512) void k_nko_mfma8(
    const unsigned short* __restrict__ Aa, const unsigned short* __restrict__ Bw,
    const float* __restrict__ bias, unsigned short* __restrict__ obf16,
    float* __restrict__ ofp32, int mode) {
  __shared__ __align__(16) unsigned short LA[4][4096];   // 128 rows x 32 K
  __shared__ __align__(16) unsigned short LB[4][8192];   // 256 rows x 32 K
  const int bt0 = blockIdx.x * 128, j0 = blockIdx.y * 256;
  const int tid = threadIdx.x;
  const int lane = tid & 63, w = tid >> 6;
  const int wr = w >> 2, wc = w & 3;          // 2 M-groups x 4 N-groups
  const int col = lane & 15, quad = lane >> 4;
  const int qsz = (quad ^ ((col >> 1) & 3)) * 8;
  f32x4 acc[4][4] = {};
  v8s rA0[4], rB0[4], rA1[4], rB1[4];

  const int o0 = tid * 8;          // dest short offset (linear)
  const int row0 = tid >> 2;       // 0..127
  const int cb0 = (((tid & 3) ^ ((tid >> 3) & 3))) * 8;   // swizzled src shorts

#define NK_STAGE(kt)                                                          \
  {                                                                           \
    const int kc_ = (kt) * 32;                                                \
    __builtin_amdgcn_global_load_lds(                                         \
        (const __attribute__((address_space(1))) void*)(Aa +                  \
            (size_t)(bt0 + row0) * E_ + kc_ + cb0),                           \
        (__attribute__((address_space(3))) void*)&LA[(kt) & 3][o0], 16, 0, 0);\
    __builtin_amdgcn_global_load_lds(                                         \
        (const __attribute__((address_space(1))) void*)(Bw +                  \
            (size_t)(j0 + row0) * E_ + kc_ + cb0),                            \
        (__attribute__((address_space(3))) void*)&LB[(kt) & 3][o0], 16, 0, 0);\
    __builtin_amdgcn_global_load_lds(                                         \
        (const __attribute__((address_space(1))) void*)(Bw +                  \
            (size_t)(j0 + 128 + row0) * E_ + kc_ + cb0),                      \
        (__attribute__((address_space(3))) void*)&LB[(kt) & 3][o0 + 4096],    \
        16, 0, 0);                                                            \
  }
#define NK_READ(RA, RB, kt)                                                   \
  {                                                                           \
    _Pragma("unroll") for (int i_ = 0; i_ < 4; ++i_) {                        \
      const int row_ = wr * 64 + i_ * 16 + col;                               \
      RA[i_] = *(const v8s*)&LA[(kt) & 3][row_ * 32 + qsz];                   \
    }                                                                         \
    _Pragma("unroll") for (int j_ = 0; j_ < 4; ++j_) {                        \
      const int row_ = wc * 64 + j_ * 16 + col;                               \
      RB[j_] = *(const v8s*)&LB[(kt) & 3][row_ * 32 + qsz];                   \
    }                                                                         \
  }
#define NK_MFMA(RA, RB)                                                       \
  __builtin_amdgcn_s_setprio(1);                                              \
  _Pragma("unroll") for (int i_ = 0; i_ < 4; ++i_)                            \
    _Pragma("unroll") for (int j_ = 0; j_ < 4; ++j_)                          \
      acc[i_][j_] = __builtin_amdgcn_mfma_f32_16x16x32_bf16(                  \
          RA[i_], RB[j_], acc[i_][j_], 0, 0, 0);                              \
  __builtin_amdgcn_s_setprio(0);

  NK_STAGE(0); NK_STAGE(1); NK_STAGE(2); NK_STAGE(3);
  asm volatile("s_waitcnt vmcnt(3)" ::: "memory");
  asm volatile("s_barrier" ::: "memory");
  NK_READ(rA0, rB0, 0);
  asm volatile("s_waitcnt lgkmcnt(0)" ::: "memory");

#pragma unroll 1
  for (int s = 0; s < 28; s += 2) {
    NK_READ(rA1, rB1, s + 1);
    NK_STAGE(s + 4);
    NK_MFMA(rA0, rB0);
    NK_READ(rA0, rB0, s + 2);
    NK_STAGE(s + 5);
    NK_MFMA(rA1, rB1);
    asm volatile("s_waitcnt vmcnt(3)" ::: "memory");
    asm volatile("s_barrier" ::: "memory");
  }
  // s = 28: no stages remain; drain last tile (31)
  NK_READ(rA1, rB1, 29);
  NK_MFMA(rA0, rB0);
  NK_READ(rA0, rB0, 30);
  NK_MFMA(rA1, rB1);
  asm volatile("s_waitcnt vmcnt(0)" ::: "memory");
  asm volatile("s_barrier" ::: "memory");
  // s = 30
  NK_READ(rA1, rB1, 31);
  NK_MFMA(rA0, rB0);
  NK_MFMA(rA1, rB1);

#undef NK_MFMA
#undef NK_READ
#undef NK_STAGE

#pragma unroll
  for (int j = 0; j < 4; ++j) {
    const int n = j0 + wc * 64 + j * 16 + col;   // 0..1023
    const float bv = bias[n];
    const int h = n >> 6, dd = n & 63;
#pragma unroll
    for (int i = 0; i < 4; ++i) {
      const int mbase = bt0 + wr * 64 + i * 16 + quad * 4;
#pragma unroll
      for (int r = 0; r < 4; ++r) {
        const int m = mbase + r;
        const float val = acc[i][j][r] + bv;
        if (mode == 0) {
          const int b = m >> 12, t = m & (T_ - 1);
          obf16[((size_t)(b * H_ + h) * T_ + t) * D_ + dd] = f2bf(val);
        } else {
          ofp32[(size_t)m * E_ + n] = val;
        }
      }
    }
  }
}

// ---------------------------------------------------------------------------
// Features via MFMA, round-16: norm phase parallelized across threads.
// Old: per wave, 32 sequential rows x 6-step shfl_xor chain (latency-bound,
// MfmaUtil 1.9%). New: 256 threads <-> 128 rows x 2 halves; each thread
// loads 8 float4 (vectorized), register-accumulates sum-of-squares, ONE
// shfl_xor(1) to combine the row, then 4x ds_write_b128 per buffer (2-way
// bank aliasing = free). Serial depth ~192 cross-lane ops -> 1.
// ---------------------------------------------------------------------------
__global__ __launch_bounds__(256) void k_feat_mfma(
    const float* __restrict__ xin, const float* __restrict__ poly_w,
    const float* __restrict__ omega, const float* __restrict__ qnod,
    const float* __restrict__ qwt, unsigned short* __restrict__ pqb,
    unsigned short* __restrict__ fqb) {
  __shared__ __align__(16) unsigned short XH[128 * 72];
  __shared__ __align__(16) unsigned short XL[128 * 72];
  __shared__ __align__(16) unsigned short Bs[80 * 72];
  const int bh = blockIdx.x >> 5;
  const int t0 = (blockIdx.x & 31) * 128;
  const int h = bh & (H_ - 1);
  const int tid = threadIdx.x, lane = tid & 63, w = tid >> 6;
  const int col = lane & 15, quad = lane >> 4;
  const size_t rowB = (size_t)bh * T_ + t0;

  const float s0 = qnod[0];
  const float sq2 = sqrtf(fmaxf(2.f * s0, 0.f));
  const float scale = sqrtf(fmaxf(qwt[0], 0.f)) * 0.3535533905932738f;

  // ---- norm phase: one (row,half) per thread ----
  {
    const int row = tid >> 1;        // 0..127
    const int half = tid & 1;        // 0,1
    const float* src = xin + (rowB + row) * D_ + half * 32;
    float v[32];
    float ss = 0.f;
#pragma unroll
    for (int j4 = 0; j4 < 8; ++j4) {
      const float4 f = *(const float4*)(src + j4 * 4);
      v[j4 * 4 + 0] = f.x; v[j4 * 4 + 1] = f.y;
      v[j4 * 4 + 2] = f.z; v[j4 * 4 + 3] = f.w;
      ss += f.x * f.x + f.y * f.y + f.z * f.z + f.w * f.w;
    }
    ss += __shfl_xor(ss, 1);
    const float rn = 1.0f / fmaxf(sqrtf(ss), 1e-12f);
#pragma unroll
    for (int j8 = 0; j8 < 4; ++j8) {
      v8s hv, lv;
#pragma unroll
      for (int j = 0; j < 8; ++j) {
        const float xn = v[j8 * 8 + j] * rn;
        const unsigned short hi = f2bf(xn);
        hv[j] = (short)hi;
        lv[j] = (short)f2bf(xn - bf2f(hi));
      }
      *(v8s*)&XH[row * 72 + half * 32 + j8 * 8] = hv;
      *(v8s*)&XL[row * 72 + half * 32 + j8 * 8] = lv;
    }
  }
  {
    const int base = tid * 16;
#pragma unroll
    for (int j4 = 0; j4 < 4; ++j4) {
      const int idx = base + j4 * 4;
      const int d = idx >> 6, p = idx & 63;
      const float4 v = *(const float4*)(poly_w + (size_t)h * 4096 + idx);
      Bs[(p + 0) * 72 + d] = f2bf(v.x);
      Bs[(p + 1) * 72 + d] = f2bf(v.y);
      Bs[(p + 2) * 72 + d] = f2bf(v.z);
      Bs[(p + 3) * 72 + d] = f2bf(v.w);
    }
    if (tid < 128) {
      const int idx = tid * 4;
      const int d = idx >> 3, m0 = idx & 7;
      const float4 v = *(const float4*)(omega + (size_t)h * 512 + idx);
      Bs[(64 + m0 + 0) * 72 + d] = f2bf(v.x);
      Bs[(64 + m0 + 1) * 72 + d] = f2bf(v.y);
      Bs[(64 + m0 + 2) * 72 + d] = f2bf(v.z);
      Bs[(64 + m0 + 3) * 72 + d] = f2bf(v.w);
    }
  }
  __syncthreads();
  f32x4 acc[2][5] = {};
#pragma unroll
  for (int kk = 0; kk < 2; ++kk) {
    v8s ah[2], al[2];
#pragma unroll
    for (int i = 0; i < 2; ++i) {
      const int mo = ((2 * w + i) * 16 + col) * 72 + kk * 32 + quad * 8;
      ah[i] = *(const v8s*)&XH[mo];
      al[i] = *(const v8s*)&XL[mo];
    }
#pragma unroll
    for (int nt = 0; nt < 5; ++nt) {
      const v8s bb = *(const v8s*)&Bs[(nt * 16 + col) * 72 + kk * 32 + quad * 8];
#pragma unroll
      for (int i = 0; i < 2; ++i) {
        acc[i][nt] = __builtin_amdgcn_mfma_f32_16x16x32_bf16(ah[i], bb, acc[i][nt], 0, 0, 0);
        acc[i][nt] = __builtin_amdgcn_mfma_f32_16x16x32_bf16(al[i], bb, acc[i][nt], 0, 0, 0);
      }
    }
  }
#pragma unroll
  for (int i = 0; i < 2; ++i) {
#pragma unroll
    for (int r = 0; r < 4; ++r) {
      const int t = (2 * w + i) * 16 + quad * 4 + r;
#pragma unroll
      for (int nt = 0; nt < 4; ++nt) {
        const float c = acc[i][nt][r];
        pqb[(rowB + t) * P_ + nt * 16 + col] = f2bf(c * c * 0.125f);
      }
      if (col < 8) {
        const float c = acc[i][4][r];
        const float z = fminf(fmaxf(c * sq2 - s0, -20.f), 20.f);
        fqb[(rowB + t) * M_ + col] = f2bf(expf(z) * scale);
      }
    }
  }
}

// ---------------------------------------------------------------------------
// Phase A via MFMA (unchanged)
// ---------------------------------------------------------------------------
__global__ __launch_bounds__(512) void k_phaseA(
    const unsigned short* __restrict__ pkb, const unsigned short* __restrict__ fkb,
    const unsigned short* __restrict__ vbf, unsigned short* __restrict__ kvch,
    float* __restrict__ ksum) {
  __shared__ __align__(16) unsigned short VT[64 * 72];
  __shared__ __align__(16) unsigned short pkT[64 * 72];
  __shared__ __align__(16) unsigned short fkT[8 * 72];
  const int bh = blockIdx.x & (BH_ - 1);
  const int c = blockIdx.x >> 5;
  const size_t rowC = (size_t)bh * T_ + (size_t)c * CH_;
  const int tid = threadIdx.x, lane = tid & 63, w = tid >> 6;
  const int col = lane & 15, quad = lane >> 4;
  const int nb = w * 64;
  f32x4 acc[4][4] = {};
  float ks[4] = {0.f, 0.f, 0.f, 0.f};

  for (int st = 0; st < 4; ++st) {
    const size_t t0 = rowC + st * 64;
    __syncthreads();
#pragma unroll
    for (int ps = 0; ps < 2; ++ps) {
      const int idx = ps * 512 + tid;
      const int t = idx >> 4, dg = (idx & 15) * 4;
      const ushort4 v = *(const ushort4*)(vbf + (t0 + t) * D_ + dg);
      VT[(dg + 0) * 72 + t] = v.x;
      VT[(dg + 1) * 72 + t] = v.y;
      VT[(dg + 2) * 72 + t] = v.z;
      VT[(dg + 3) * 72 + t] = v.w;
    }
    {
      const int t = tid >> 3, pg = (tid & 7) * 8;
      const v8s pv = *(const v8s*)(pkb + (t0 + t) * P_ + pg);
#pragma unroll
      for (int j = 0; j < 8; ++j) pkT[(pg + j) * 72 + t] = (unsigned short)pv[j];
    }
    if (tid < 64) {
      const v8s fv = *(const v8s*)(fkb + (t0 + tid) * M_);
#pragma unroll
      for (int j = 0; j < 8; ++j) fkT[j * 72 + tid] = (unsigned short)fv[j];
    }
    __syncthreads();
#pragma unroll
    for (int kk = 0; kk < 2; ++kk) {
      v8s a[4];
#pragma unroll
      for (int mt = 0; mt < 4; ++mt)
        a[mt] = *(const v8s*)&VT[(mt * 16 + col) * 72 + kk * 32 + quad * 8];
#pragma unroll
      for (int nt = 0; nt < 4; ++nt) {
        const int pm = nb + nt * 16 + col;
        const int p = pm >> 3, m8 = pm & 7;
        const v8s pkv = *(const v8s*)&pkT[p * 72 + kk * 32 + quad * 8];
        const v8s fkv = *(const v8s*)&fkT[m8 * 72 + kk * 32 + quad * 8];
        v8s bfrag;
        float kss = 0.f;
#pragma unroll
        for (int j = 0; j < 8; ++j) {
          const float v = bf2f((unsigned short)pkv[j]) * bf2f((unsigned short)fkv[j]);
          kss += v;
          bfrag[j] = (short)f2bf(v);
        }
        ks[nt] += kss;
#pragma unroll
        for (int mt = 0; mt < 4; ++mt)
          acc[mt][nt] = __builtin_amdgcn_mfma_f32_16x16x32_bf16(a[mt], bfrag, acc[mt][nt], 0, 0, 0);
      }
    }
  }
  const size_t base = (size_t)(c * BH_ + bh) * D_ * F_;
#pragma unroll
  for (int nt = 0; nt < 4; ++nt) {
    const int pm = nb + nt * 16 + col;
#pragma unroll
    for (int mt = 0; mt < 4; ++mt) {
#pragma unroll
      for (int r = 0; r < 4; ++r) {
        const int d = mt * 16 + quad * 4 + r;
        kvch[base + (size_t)d * F_ + pm] = f2bf(acc[mt][nt][r]);
      }
    }
    float kv_ = ks[nt];
    kv_ += __shfl_xor(kv_, 16);
    kv_ += __shfl_xor(kv_, 32);
    if (quad == 0) ksum[(size_t)(c * BH_ + bh) * F_ + pm] = kv_;
  }
}

// ---------------------------------------------------------------------------
__global__ __launch_bounds__(256) void k_scan_kv(unsigned short* __restrict__ kvch) {
  const size_t s = (size_t)blockIdx.x * 256 + threadIdx.x;
  const size_t stride = (size_t)BH_ * D_ * F_;
  unsigned short v[NC_];
#pragma unroll
  for (int c = 0; c < NC_; ++c) v[c] = kvch[(size_t)c * stride + s];
  float run = 0.f;
#pragma unroll
  for (int c = 0; c < NC_; ++c) {
    const float t = bf2f(v[c]);
    kvch[(size_t)c * stride + s] = f2bf(run);
    run += t;
  }
}

__global__ __launch_bounds__(256) void k_scan_ks(float* __restrict__ ksum) {
  const int s = blockIdx.x * 256 + threadIdx.x;
  const int stride = BH_ * F_;
  float v[NC_];
#pragma unroll
  for (int c = 0; c < NC_; ++c) v[c] = ksum[c * stride + s];
  float run = 0.f;
#pragma unroll
  for (int c = 0; c < NC_; ++c) {
    const float t = v[c];
    ksum[c * stride + s] = run;
    run += t;
  }
}

// ---------------------------------------------------------------------------
// Fused scores+intra (round-11 version: pk/fk LDS staging + 3rd-MFMA fusion)
// ---------------------------------------------------------------------------
__global__ __launch_bounds__(256) void k_sintra(
    const unsigned short* __restrict__ pqb, const unsigned short* __restrict__ fqb,
    const unsigned short* __restrict__ pkb, const unsigned short* __restrict__ fkb,
    const unsigned short* __restrict__ vbf, float* __restrict__ obuf,
    float* __restrict__ nrmbuf) {
  __shared__ __align__(16) unsigned short S_lds[128 * 136];
  __shared__ __align__(16) unsigned short VT[64 * 136];
  __shared__ __align__(16) unsigned short pkT[128 * 72];
  __shared__ __align__(16) unsigned short fkT[128 * 8];
  const int bh = blockIdx.x & (BH_ - 1);
  const int tq = blockIdx.x >> 5;
  const int c = tq >> 1, h2 = tq & 1;
  const size_t rowT = (size_t)bh * T_ + (size_t)tq * 128;
  const size_t rowC = (size_t)bh * T_ + (size_t)c * CH_;
  const int tid = threadIdx.x, lane = tid & 63, w = tid >> 6;
  const int col = lane & 15, quad = lane >> 4;

  const v8s vzero = {};
  v8s bq[2][2], bqf[2];
#pragma unroll
  for (int i = 0; i < 2; ++i) {
    const size_t qrow = rowT + (2 * w + i) * 16 + col;
    bq[i][0] = *(const v8s*)(pqb + qrow * P_ + quad * 8);
    bq[i][1] = *(const v8s*)(pqb + qrow * P_ + 32 + quad * 8);
    const v8s fv = *(const v8s*)(fqb + qrow * M_);
    bqf[i] = (quad == 0) ? fv : vzero;
  }
  f32x4 acc[2][4] = {};
  float rs[2] = {0.f, 0.f};

  const int vd = tid & 63, vg = tid >> 6;

  for (int sl = 0; sl <= h2; ++sl) {
    const size_t rowS = rowC + (size_t)sl * 128;
    __syncthreads();
#pragma unroll
    for (int c4 = 0; c4 < 4; ++c4) {
      const int g = c4 * 256 + tid;
      const int row = g >> 3, ch = g & 7;
      *(v8s*)&pkT[row * 72 + ch * 8] =
          *(const v8s*)(pkb + (rowS + row) * P_ + ch * 8);
    }
    if (tid < 128)
      *(v8s*)&fkT[tid * 8] = *(const v8s*)(fkb + (rowS + tid) * M_);
#pragma unroll
    for (int j8 = 0; j8 < 4; ++j8) {
      const int s0 = vg * 32 + j8 * 8;
      v8s pv;
#pragma unroll
      for (int k = 0; k < 8; ++k)
        pv[k] = (short)vbf[(rowS + s0 + k) * D_ + vd];
      *(v8s*)&VT[vd * 136 + s0] = pv;
    }
    __syncthreads();
    for (int si = 0; si < 8; ++si) {
      const int srow = si * 16 + col;
      const v8s a0 = *(const v8s*)&pkT[srow * 72 + quad * 8];
      const v8s a1 = *(const v8s*)&pkT[srow * 72 + 32 + quad * 8];
      const v8s af = (quad == 0) ? *(const v8s*)&fkT[srow * 8] : vzero;
#pragma unroll
      for (int i = 0; i < 2; ++i) {
        const int tt = 2 * w + i;
        const int t_rel = h2 * 128 + tt * 16 + col;
        f32x4 sp = {};
        sp = __builtin_amdgcn_mfma_f32_16x16x32_bf16(a0, bq[i][0], sp, 0, 0, 0);
        sp = __builtin_amdgcn_mfma_f32_16x16x32_bf16(a1, bq[i][1], sp, 0, 0, 0);
        f32x4 spf = {};
        spf = __builtin_amdgcn_mfma_f32_16x16x32_bf16(af, bqf[i], spf, 0, 0, 0);
        ushort4 pk4;
        float partial = 0.f;
#pragma unroll
        for (int r = 0; r < 4; ++r) {
          const int s_in = si * 16 + quad * 4 + r;
          float val = sp[r] * spf[r];
          const int s_rel = sl * 128 + s_in;
          val = (s_rel <= t_rel) ? val : 0.f;
          partial += val;
          ((unsigned short*)&pk4)[r] = f2bf(val);
        }
        rs[i] += partial;
        *(ushort4*)&S_lds[(tt * 16 + col) * 136 + si * 16 + quad * 4] = pk4;
      }
    }
    __syncthreads();
#pragma unroll
    for (int i = 0; i < 2; ++i) {
      const int tt = 2 * w + i;
#pragma unroll
      for (int kk = 0; kk < 4; ++kk) {
        const v8s sa = *(const v8s*)&S_lds[(tt * 16 + col) * 136 + kk * 32 + quad * 8];
#pragma unroll
        for (int dt = 0; dt < 4; ++dt) {
          const v8s vb8 = *(const v8s*)&VT[(dt * 16 + col) * 136 + kk * 32 + quad * 8];
          acc[i][dt] = __builtin_amdgcn_mfma_f32_16x16x32_bf16(sa, vb8, acc[i][dt], 0, 0, 0);
        }
      }
    }
  }
#pragma unroll
  for (int i = 0; i < 2; ++i) {
#pragma unroll
    for (int dt = 0; dt < 4; ++dt) {
#pragma unroll
      for (int r = 0; r < 4; ++r) {
        const int t = (2 * w + i) * 16 + quad * 4 + r;
        obuf[(rowT + t) * D_ + dt * 16 + col] = acc[i][dt][r];
      }
    }
    rs[i] += __shfl_xor(rs[i], 16);
    rs[i] += __shfl_xor(rs[i], 32);
  }
  if (lane < 16) {
    const size_t nbase = (size_t)(c * BH_ + bh) * CH_ + h2 * 128;
    nrmbuf[nbase + (2 * w + 0) * 16 + lane] = rs[0];
    nrmbuf[nbase + (2 * w + 1) * 16 + lane] = rs[1];
  }
}

// ---------------------------------------------------------------------------
// Hist via MFMA (unchanged)
// ---------------------------------------------------------------------------
__global__ __launch_bounds__(256) void k_hist(
    const unsigned short* __restrict__ pqb, const unsigned short* __restrict__ fqb,
    const unsigned short* __restrict__ kvch, const float* __restrict__ ksum,
    const float* __restrict__ nrmbuf, const float* __restrict__ obuf,
    unsigned short* __restrict__ obf) {
  __shared__ __align__(16) unsigned short QF_lds[128 * 72];
  __shared__ __align__(16) unsigned short KV_lds[64 * 72];
  __shared__ float kp_lds[F_];
  __shared__ float nhs[128];
  const int half = blockIdx.x & 1;
  const int bh = (blockIdx.x >> 1) & (BH_ - 1);
  const int c = blockIdx.x >> 6;
  const int b = bh >> 4, h = bh & (H_ - 1);
  const int tid = threadIdx.x, lane = tid & 63, w = tid >> 6;
  const int col = lane & 15, quad = lane >> 4;
  const size_t rowQ = (size_t)bh * T_ + (size_t)c * CH_ + half * 128;
  const size_t kvbase = (size_t)(c * BH_ + bh) * D_ * F_;

  const int tr = tid >> 1, side = tid & 1;
  float fqr[8];
  {
    const v8s fv = *(const v8s*)(fqb + (rowQ + tr) * M_);
#pragma unroll
    for (int j = 0; j < 8; ++j) fqr[j] = bf2f((unsigned short)fv[j]);
    if (tid < 128)
      *(float4*)(&kp_lds[tid * 4]) =
          *(const float4*)(ksum + (size_t)(c * BH_ + bh) * F_ + tid * 4);
  }
  f32x4 acc[2][4] = {};
  float nh_part = 0.f;
  const int gr = tid & 7, d0 = tid >> 3;

  for (int pmt = 0; pmt < 8; ++pmt) {
    __syncthreads();
#pragma unroll
    for (int pp = 0; pp < 2; ++pp) {
      const int d = d0 + pp * 32;
      *(v8s*)&KV_lds[d * 72 + gr * 8] =
          *(const v8s*)(kvch + kvbase + (size_t)d * F_ + pmt * 64 + gr * 8);
    }
    {
      const v8s pq8 = *(const v8s*)(pqb + (rowQ + tr) * P_ + pmt * 8);
#pragma unroll
      for (int pp = 0; pp < 4; ++pp) {
        const int pl = side * 4 + pp;
        const float pqf = bf2f((unsigned short)pq8[pl]);
        const int kb_ = (pmt * 8 + pl) * 8;
        v8s o;
#pragma unroll
        for (int j = 0; j < 8; ++j) {
          const float v = pqf * fqr[j];
          nh_part += v * kp_lds[kb_ + j];
          o[j] = (short)f2bf(v);
        }
        *(v8s*)&QF_lds[tr * 72 + pl * 8] = o;
      }
    }
    __syncthreads();
#pragma unroll
    for (int kk = 0; kk < 2; ++kk) {
      v8s a[2], bb[4];
#pragma unroll
      for (int i = 0; i < 2; ++i)
        a[i] = *(const v8s*)&QF_lds[((2 * w + i) * 16 + col) * 72 + kk * 32 + quad * 8];
#pragma unroll
      for (int j = 0; j < 4; ++j)
        bb[j] = *(const v8s*)&KV_lds[(j * 16 + col) * 72 + kk * 32 + quad * 8];
#pragma unroll
      for (int i = 0; i < 2; ++i)
#pragma unroll
        for (int j = 0; j < 4; ++j)
          acc[i][j] = __builtin_amdgcn_mfma_f32_16x16x32_bf16(a[i], bb[j], acc[i][j], 0, 0, 0);
    }
  }
  {
    const float nh = nh_part + __shfl_xor(nh_part, 1);
    if (!(tid & 1)) nhs[tr] = nh;
  }
  __syncthreads();
  const size_t nbase = (size_t)(c * BH_ + bh) * CH_ + half * 128;
#pragma unroll
  for (int i = 0; i < 2; ++i) {
#pragma unroll
    for (int r = 0; r < 4; ++r) {
      const int t = (2 * w + i) * 16 + quad * 4 + r;
      const float nrm = nhs[t] + nrmbuf[nbase + t] + 1e-6f;
      const float rcp = 1.0f / nrm;
#pragma unroll
      for (int j = 0; j < 4; ++j) {
        const int d = j * 16 + col;
        const float val = (obuf[(rowQ + t) * D_ + d] + acc[i][j][r]) * rcp;
        obf[(size_t)(b * T_ + c * CH_ + half * 128 + t) * E_ + h * 64 + d] = f2bf(val);
      }
    }
  }
}

// ---------------------------------------------------------------------------
extern "C" void kernel_launch(void* const* d_in, const int* in_sizes, int n_in,
                              void* d_out, int out_size, void* d_ws, size_t ws_size,
                              hipStream_t stream) {
  (void)in_sizes; (void)n_in; (void)out_size; (void)ws_size;
  const float* x      = (const float*)d_in[0];
  const float* qkv_w  = (const float*)d_in[1];
  const float* qkv_b  = (const float*)d_in[2];
  const float* out_w  = (const float*)d_in[3];
  const float* out_b  = (const float*)d_in[4];
  const float* omega  = (const float*)d_in[5];
  const float* poly_w = (const float*)d_in[6];
  const float* qnod   = (const float*)d_in[7];
  const float* qwt    = (const float*)d_in[8];
  float* ws = (float*)d_ws;
  float* qb   = ws + OFF_Q;
  float* kb   = ws + OFF_K;
  unsigned short* vbf = (unsigned short*)(ws + OFF_V);
  unsigned short* fqb = (unsigned short*)(ws + OFF_FQ);
  unsigned short* fkb = (unsigned short*)(ws + OFF_FK);
  float* ksb  = ws + OFF_KS;
  float* nrmb = ws + OFF_NRM;
  float* ob   = ws + OFF_O;
  unsigned short* kvb = (unsigned short*)(ws + OFF_KV);
  unsigned short* pqb = kvb + 16777216;
  unsigned short* pkb = pqb + SZ_BHTD;
  unsigned short* xhi  = kvb;
  unsigned short* xlo  = kvb + SZ_BHTD;
  unsigned short* wqkv = kvb + 2 * SZ_BHTD;
  unsigned short* obf   = (unsigned short*)kb;
  unsigned short* woutb = (unsigned short*)(ws + OFF_V);  // over dead v (post-sintra)
  float* outp = (float*)d_out;

  hipLaunchKernelGGL(k_split_x, dim3(8192), dim3(256), 0, stream, x, xhi, xlo);
  hipLaunchKernelGGL(k_cast_w, dim3(3072), dim3(256), 0, stream, qkv_w, wqkv);
  hipLaunchKernelGGL(k_qk_mfma8, dim3(BT_ / 256, 8), dim3(512), 0, stream,
                     xhi, xlo, wqkv, qkv_b, qb, kb);
  hipLaunchKernelGGL(k_nko_mfma8, dim3(BT_ / 128, 4), dim3(512), 0, stream,
                     xhi, wqkv + (size_t)2048 * E_, qkv_b + 2048, vbf,
                     (float*)nullptr, 0);
  hipLaunchKernelGGL(k_feat_mfma, dim3(1024), dim3(256), 0, stream,
                     qb, poly_w, omega, qnod, qwt, pqb, fqb);
  hipLaunchKernelGGL(k_feat_mfma, dim3(1024), dim3(256), 0, stream,
                     kb, poly_w, omega, qnod, qwt, pkb, fkb);
  hipLaunchKernelGGL(k_phaseA, dim3(NC_ * BH_), dim3(512), 0, stream,
                     pkb, fkb, vbf, kvb, ksb);
  hipLaunchKernelGGL(k_scan_kv, dim3(4096), dim3(256), 0, stream, kvb);
  hipLaunchKernelGGL(k_scan_ks, dim3(64), dim3(256), 0, stream, ksb);
  hipLaunchKernelGGL(k_sintra, dim3(BH_ * 32), dim3(256), 0, stream,
                     pqb, fqb, pkb, fkb, vbf, ob, nrmb);
  hipLaunchKernelGGL(k_cast_w, dim3(1024), dim3(256), 0, stream, out_w, woutb);
  hipLaunchKernelGGL(k_hist, dim3(NC_ * BH_ * 2), dim3(256), 0, stream,
                     pqb, fqb, kvb, ksb, nrmb, ob, obf);
  hipLaunchKernelGGL(k_nko_mfma8, dim3(BT_ / 128, 4), dim3(512), 0, stream,
                     obf, woutb, out_b, (unsigned short*)nullptr, outp, 1);
}